// Round 11
// baseline (1017.711 us; speedup 1.0000x reference)
//
#include <hip/hip_runtime.h>
#include <cstdio>

// Problem constants
#define BATCH 256
#define SEQL 256
#define NPOS 259            // 3 + SEQL
#define TTOK (BATCH*NPOS)   // 66304 = 518 * 128
#define HD 128
#define NHEAD 8
#define FF 512
#define DEPTH 4
#define CVOC 50001

typedef unsigned short u16;
typedef unsigned int u32;
typedef __bf16 bf16x8 __attribute__((ext_vector_type(8)));
typedef float f32x4 __attribute__((ext_vector_type(4)));
typedef float f32x16 __attribute__((ext_vector_type(16)));

typedef const __attribute__((address_space(1))) u32 gas_u32;
typedef __attribute__((address_space(3))) u32 las_u32;
#define GLOAD16(gptr, lptr) \
  __builtin_amdgcn_global_load_lds((gas_u32*)(gptr), (las_u32*)(lptr), 16, 0, 0)

// SCALE * log2(e): q pre-scaled so attention softmax can use native exp2
#define QSCALE 0.36067376022224085f

__device__ __forceinline__ u16 f2bf(float f) {
  u32 i = __float_as_uint(f);
  u32 r = (i + 0x7FFFu + ((i >> 16) & 1u)) >> 16;   // RNE
  return (u16)r;
}

// ---------------------------------------------------------------- merged transpose + downcast
__global__ void k_transpose_all(const float* __restrict__ qkv_w, const float* __restrict__ out_w,
                                const float* __restrict__ w1, const float* __restrict__ w2,
                                u16* __restrict__ wT) {
  int idx = blockIdx.x * 256 + threadIdx.x;
  const float* in; int K, N, local;
  if (idx < 196608)      { in = qkv_w; K = 128; N = 384; local = idx; }
  else if (idx < 262144) { in = out_w; K = 128; N = 128; local = idx - 196608; }
  else if (idx < 524288) { in = w1;    K = 128; N = 512; local = idx - 262144; }
  else if (idx < 786432) { in = w2;    K = 512; N = 128; local = idx - 524288; }
  else return;
  int k = local % K; int rem = local / K; int n = rem % N; int d = rem / N;
  wT[idx] = f2bf(in[(d * K + k) * N + n]);
}

// ---------------------------------------------------------------- build x (+ fused layer-0 LN1)
__global__ __launch_bounds__(128)
void k_build(const int* __restrict__ item_seq, const int* __restrict__ act_seq,
             const int* __restrict__ tdiff,
             const int* __restrict__ ucv, const int* __restrict__ ucl, const float* __restrict__ unum,
             const int* __restrict__ icv, const int* __restrict__ icl, const float* __restrict__ inum,
             const float* __restrict__ item_t, const float* __restrict__ act_t,
             const float* __restrict__ time_t, const float* __restrict__ cat_t,
             const float* __restrict__ numW, const float* __restrict__ gtok,
             const float* __restrict__ g, const float* __restrict__ be,
             float* __restrict__ x, u16* __restrict__ src) {
  int pos = blockIdx.x, b = blockIdx.y, h = threadIdx.x;
  float v;
  if (pos == 0) {
    v = gtok[h];
  } else if (pos <= 2) {
    const int* cv = (pos == 1) ? ucv : icv;
    const int* cl = (pos == 1) ? ucl : icl;
    const float* nm = (pos == 1) ? unum : inum;
    float acc = 0.f;
    for (int f = 0; f < 8; ++f) {
      float s = 0.f;
      for (int k = 0; k < 8; ++k) {
        int idx = cv[(b * 8 + f) * 8 + k];
        s += cat_t[((size_t)f * CVOC + idx) * HD + h];
      }
      acc += s / (float)cl[b * 8 + f];
    }
    for (int f = 0; f < 4; ++f)
      for (int d = 0; d < 32; ++d)
        acc += nm[(b * 4 + f) * 32 + d] * numW[(f * 32 + d) * HD + h];
    v = acc * (1.f / 12.f);
  } else {
    int l = pos - 3;
    v = item_t[(size_t)item_seq[b * SEQL + l] * HD + h]
      + act_t[(size_t)act_seq[b * SEQL + l] * HD + h]
      + time_t[(size_t)tdiff[b * SEQL + l] * HD + h];
  }
  size_t t = (size_t)b * NPOS + pos;
  x[t * HD + h] = v;
  __shared__ float red[2][2];
  float s = v, s2 = v * v;
  #pragma unroll
  for (int o = 32; o; o >>= 1) { s += __shfl_xor(s, o); s2 += __shfl_xor(s2, o); }
  if ((h & 63) == 0) { red[h >> 6][0] = s; red[h >> 6][1] = s2; }
  __syncthreads();
  float S = red[0][0] + red[1][0], S2 = red[0][1] + red[1][1];
  float mean = S * (1.f / HD);
  float rstd = rsqrtf(S2 * (1.f / HD) - mean * mean + 1e-5f);
  src[t * HD + h] = f2bf((v - mean) * rstd * g[h] + be[h]);
}

// ---------------------------------------------------------------- GEMM, A-resident multi-N (layer-0 QKV)
template <int NCH, int ACT, bool QS>
__global__ __launch_bounds__(256)
void k_gemm_nres(const u16* __restrict__ X, const u16* __restrict__ WT,
                 const float* __restrict__ bias, u16* __restrict__ outp) {
  const int K = 128, N = NCH * 128;
  __shared__ __align__(16) u16 lA[4][128 * 32];
  __shared__ __align__(16) u16 lB[128 * 32];
  const int tid = threadIdx.x;
  const int wave = tid >> 6, lane = tid & 63;
  const int row0 = blockIdx.x * 128;
  const int wr = (wave >> 1) * 64, wc = (wave & 1) * 64;
  const int sr = lane >> 2;
  const int sc = ((lane & 3) ^ ((lane >> 3) & 3)) << 3;
  const int q = lane & 15;
  const int cg = lane >> 4;
  const int rdoff = ((cg ^ ((q >> 1) & 3)) << 3);
  #pragma unroll
  for (int s = 0; s < 8; ++s) {
    int kt = s & 3, rg = 2 * wave + (s >> 2);
    int r = rg * 16 + sr;
    GLOAD16(X + (size_t)(row0 + r) * K + kt * 32 + sc, &lA[kt][rg * 512]);
  }
  const u16* gB0 = WT + (size_t)(wave * 16 + sr) * K + sc;
  const u16* gB1 = WT + (size_t)(64 + wave * 16 + sr) * K + sc;
  u16* lB0 = &lB[wave * 512];
  u16* lB1 = &lB[2048 + wave * 512];
  for (int nc = 0; nc < NCH; ++nc) {
    const size_t nbase = (size_t)nc * 128 * K;
    f32x4 acc[4][4] = {};
    for (int k0 = 0; k0 < K; k0 += 32) {
      __syncthreads();
      GLOAD16(gB0 + nbase + k0, lB0);
      GLOAD16(gB1 + nbase + k0, lB1);
      __syncthreads();
      const int kt = k0 >> 5;
      bf16x8 af[4], bf[4];
      #pragma unroll
      for (int i = 0; i < 4; ++i)
        af[i] = *(const bf16x8*)&lA[kt][(wr + i * 16 + q) * 32 + rdoff];
      #pragma unroll
      for (int j = 0; j < 4; ++j)
        bf[j] = *(const bf16x8*)&lB[(wc + j * 16 + q) * 32 + rdoff];
      #pragma unroll
      for (int i = 0; i < 4; ++i)
        #pragma unroll
        for (int j = 0; j < 4; ++j)
          acc[i][j] = __builtin_amdgcn_mfma_f32_16x16x32_bf16(af[i], bf[j], acc[i][j], 0, 0, 0);
    }
    const int rg4 = cg * 4;
    const float scl = (QS && nc == 0) ? QSCALE : 1.f;
    #pragma unroll
    for (int i = 0; i < 4; ++i) {
      #pragma unroll
      for (int j = 0; j < 4; ++j) {
        int col = nc * 128 + wc + j * 16 + q;
        float bv = bias[col];
        #pragma unroll
        for (int jj = 0; jj < 4; ++jj) {
          int row = row0 + wr + i * 16 + rg4 + jj;
          float v = acc[i][j][jj] + bv;
          if (ACT == 1) v = 0.5f * v * (1.f + erff(v * 0.70710678118654752f));
          if (QS) v *= scl;
          outp[(size_t)row * N + col] = f2bf(v);
        }
      }
    }
  }
}

// ---------------------------------------------------------------- FUSED: residGEMM+LN -> LDS A -> multi-N GEMM
// Stage 1: xnew = xio + X@WT1 + bias1 (K1); LN(g,be) -> bf16 scattered into swizzled sA.
// Stage 2: out2 = act2(LN @ WT2 + bias2), WT2 K=128, NCH2 n-chunks of 128.
// LN values never touch HBM. Output bit-identical to the unfused pair.
template <int K1, int NCH2, int ACT2, bool QS2>
__global__ __launch_bounds__(256)
void k_fused(const u16* __restrict__ X, const u16* __restrict__ WT1,
             const float* __restrict__ bias1, float* __restrict__ xio,
             const float* __restrict__ g, const float* __restrict__ be,
             const u16* __restrict__ WT2, const float* __restrict__ bias2,
             u16* __restrict__ out2) {
  __shared__ __align__(16) u16 sA[4][128 * 32];   // stage1: [0]=A k-step buf; stage2: full LN'd A
  __shared__ __align__(16) u16 sB[128 * 32];
  __shared__ float part[128][2][2];
  const int tid = threadIdx.x;
  const int wave = tid >> 6, lane = tid & 63;
  const int row0 = blockIdx.x * 128;
  const int wr = (wave >> 1) * 64, wc = (wave & 1) * 64;
  const int whalf = wave & 1;
  const int sr = lane >> 2;
  const int sc = ((lane & 3) ^ ((lane >> 3) & 3)) << 3;
  const int q = lane & 15;
  const int cg = lane >> 4;
  const int rdoff = ((cg ^ ((q >> 1) & 3)) << 3);
  const int rg4 = cg * 4;
  // ---- stage 1: residual GEMM over K1
  {
    const u16* gA0 = X + (size_t)(row0 + wave * 16 + sr) * K1 + sc;
    const u16* gA1 = X + (size_t)(row0 + 64 + wave * 16 + sr) * K1 + sc;
    const u16* gB0 = WT1 + (size_t)(wave * 16 + sr) * K1 + sc;
    const u16* gB1 = WT1 + (size_t)(64 + wave * 16 + sr) * K1 + sc;
    u16* lA0 = &sA[0][wave * 512];
    u16* lA1 = &sA[0][2048 + wave * 512];
    u16* lB0 = &sB[wave * 512];
    u16* lB1 = &sB[2048 + wave * 512];
    f32x4 acc[4][4] = {};
    for (int k0 = 0; k0 < K1; k0 += 32) {
      __syncthreads();
      GLOAD16(gA0 + k0, lA0);
      GLOAD16(gA1 + k0, lA1);
      GLOAD16(gB0 + k0, lB0);
      GLOAD16(gB1 + k0, lB1);
      __syncthreads();
      bf16x8 af[4], bf[4];
      #pragma unroll
      for (int i = 0; i < 4; ++i)
        af[i] = *(const bf16x8*)&sA[0][(wr + i * 16 + q) * 32 + rdoff];
      #pragma unroll
      for (int j = 0; j < 4; ++j)
        bf[j] = *(const bf16x8*)&sB[(wc + j * 16 + q) * 32 + rdoff];
      #pragma unroll
      for (int i = 0; i < 4; ++i)
        #pragma unroll
        for (int j = 0; j < 4; ++j)
          acc[i][j] = __builtin_amdgcn_mfma_f32_16x16x32_bf16(af[i], bf[j], acc[i][j], 0, 0, 0);
    }
    // residual add + LN stats
    float ps[4][4], ps2[4][4];
    #pragma unroll
    for (int i = 0; i < 4; ++i)
      #pragma unroll
      for (int jj = 0; jj < 4; ++jj) { ps[i][jj] = 0.f; ps2[i][jj] = 0.f; }
    #pragma unroll
    for (int i = 0; i < 4; ++i) {
      #pragma unroll
      for (int j = 0; j < 4; ++j) {
        int col = wc + j * 16 + q;
        float bv = bias1[col];
        #pragma unroll
        for (int jj = 0; jj < 4; ++jj) {
          int row = row0 + wr + i * 16 + rg4 + jj;
          float xv = xio[(size_t)row * 128 + col] + acc[i][j][jj] + bv;
          acc[i][j][jj] = xv;
          ps[i][jj] += xv;
          ps2[i][jj] += xv * xv;
        }
      }
    }
    #pragma unroll
    for (int o = 1; o < 16; o <<= 1) {
      #pragma unroll
      for (int i = 0; i < 4; ++i)
        #pragma unroll
        for (int jj = 0; jj < 4; ++jj) {
          ps[i][jj]  += __shfl_xor(ps[i][jj], o);
          ps2[i][jj] += __shfl_xor(ps2[i][jj], o);
        }
    }
    if (q == 0) {
      #pragma unroll
      for (int i = 0; i < 4; ++i)
        #pragma unroll
        for (int jj = 0; jj < 4; ++jj) {
          int rl = wr + i * 16 + rg4 + jj;
          part[rl][whalf][0] = ps[i][jj];
          part[rl][whalf][1] = ps2[i][jj];
        }
    }
    __syncthreads();   // stats exchange; also separates last MFMA reads from sA overwrite
    #pragma unroll
    for (int i = 0; i < 4; ++i) {
      #pragma unroll
      for (int jj = 0; jj < 4; ++jj) {
        int rl = wr + i * 16 + rg4 + jj;
        float S  = part[rl][0][0] + part[rl][1][0];
        float S2 = part[rl][0][1] + part[rl][1][1];
        float mean = S * (1.f / 128.f);
        float rstd = rsqrtf(S2 * (1.f / 128.f) - mean * mean + 1e-5f);
        int row = row0 + rl;
        const int rsel = ((rl >> 1) & 3);
        #pragma unroll
        for (int j = 0; j < 4; ++j) {
          int col = wc + j * 16 + q;
          float xv = acc[i][j][jj];
          xio[(size_t)row * 128 + col] = xv;
          u16 lnv = f2bf((xv - mean) * rstd * g[col] + be[col]);
          // swizzled LDS scatter, bit-compatible with stage-2 reader
          sA[col >> 5][rl * 32 + ((((col >> 3) & 3) ^ rsel) << 3) + (col & 7)] = lnv;
        }
      }
    }
  }
  // ---- stage 2: LN'd A (in sA) @ WT2, NCH2 chunks of 128 cols
  const u16* gB20 = WT2 + (size_t)(wave * 16 + sr) * 128 + sc;
  const u16* gB21 = WT2 + (size_t)(64 + wave * 16 + sr) * 128 + sc;
  u16* lB0 = &sB[wave * 512];
  u16* lB1 = &sB[2048 + wave * 512];
  for (int nc = 0; nc < NCH2; ++nc) {
    const size_t nbase = (size_t)nc * 128 * 128;
    f32x4 acc[4][4] = {};
    for (int k0 = 0; k0 < 128; k0 += 32) {
      __syncthreads();     // first iter: drains LN ds_writes; later: protects lB reuse
      GLOAD16(gB20 + nbase + k0, lB0);
      GLOAD16(gB21 + nbase + k0, lB1);
      __syncthreads();
      const int kt = k0 >> 5;
      bf16x8 af[4], bf[4];
      #pragma unroll
      for (int i = 0; i < 4; ++i)
        af[i] = *(const bf16x8*)&sA[kt][(wr + i * 16 + q) * 32 + rdoff];
      #pragma unroll
      for (int j = 0; j < 4; ++j)
        bf[j] = *(const bf16x8*)&sB[(wc + j * 16 + q) * 32 + rdoff];
      #pragma unroll
      for (int i = 0; i < 4; ++i)
        #pragma unroll
        for (int j = 0; j < 4; ++j)
          acc[i][j] = __builtin_amdgcn_mfma_f32_16x16x32_bf16(af[i], bf[j], acc[i][j], 0, 0, 0);
    }
    const float scl = (QS2 && nc == 0) ? QSCALE : 1.f;
    #pragma unroll
    for (int i = 0; i < 4; ++i) {
      #pragma unroll
      for (int j = 0; j < 4; ++j) {
        int col = nc * 128 + wc + j * 16 + q;
        float bv = bias2[col];
        #pragma unroll
        for (int jj = 0; jj < 4; ++jj) {
          int row = row0 + wr + i * 16 + rg4 + jj;
          float v = acc[i][j][jj] + bv;
          if (ACT2 == 1) v = 0.5f * v * (1.f + erff(v * 0.70710678118654752f));
          if (QS2) v *= scl;
          out2[(size_t)row * (NCH2 * 128) + col] = f2bf(v);
        }
      }
    }
  }
}

// ---------------------------------------------------------------- plain residual GEMM (last MLP2)
__global__ __launch_bounds__(256)
void k_gemm_res(const u16* __restrict__ X, const u16* __restrict__ WT,
                const float* __restrict__ bias, float* __restrict__ xio, int K) {
  __shared__ __align__(16) u16 lA[128 * 32];
  __shared__ __align__(16) u16 lB[128 * 32];
  const int tid = threadIdx.x;
  const int wave = tid >> 6, lane = tid & 63;
  const int row0 = blockIdx.x * 128;
  const int wr = (wave >> 1) * 64, wc = (wave & 1) * 64;
  const int sr = lane >> 2;
  const int sc = ((lane & 3) ^ ((lane >> 3) & 3)) << 3;
  const u16* gA0 = X  + (size_t)(row0 + wave * 16 + sr) * K + sc;
  const u16* gA1 = X  + (size_t)(row0 + 64 + wave * 16 + sr) * K + sc;
  const u16* gB0 = WT + (size_t)(wave * 16 + sr) * K + sc;
  const u16* gB1 = WT + (size_t)(64 + wave * 16 + sr) * K + sc;
  u16* lA0 = &lA[wave * 512];
  u16* lA1 = &lA[2048 + wave * 512];
  u16* lB0 = &lB[wave * 512];
  u16* lB1 = &lB[2048 + wave * 512];
  const int q = lane & 15;
  const int cg = lane >> 4;
  const int rdoff = ((cg ^ ((q >> 1) & 3)) << 3);
  f32x4 acc[4][4] = {};
  for (int k0 = 0; k0 < K; k0 += 32) {
    __syncthreads();
    GLOAD16(gA0 + k0, lA0);
    GLOAD16(gA1 + k0, lA1);
    GLOAD16(gB0 + k0, lB0);
    GLOAD16(gB1 + k0, lB1);
    __syncthreads();
    bf16x8 af[4], bf[4];
    #pragma unroll
    for (int i = 0; i < 4; ++i)
      af[i] = *(const bf16x8*)&lA[(wr + i * 16 + q) * 32 + rdoff];
    #pragma unroll
    for (int j = 0; j < 4; ++j)
      bf[j] = *(const bf16x8*)&lB[(wc + j * 16 + q) * 32 + rdoff];
    #pragma unroll
    for (int i = 0; i < 4; ++i)
      #pragma unroll
      for (int j = 0; j < 4; ++j)
        acc[i][j] = __builtin_amdgcn_mfma_f32_16x16x32_bf16(af[i], bf[j], acc[i][j], 0, 0, 0);
  }
  const int rg4 = cg * 4;
  #pragma unroll
  for (int i = 0; i < 4; ++i) {
    #pragma unroll
    for (int j = 0; j < 4; ++j) {
      int col = wc + j * 16 + q;
      float bv = bias[col];
      #pragma unroll
      for (int jj = 0; jj < 4; ++jj) {
        int row = row0 + wr + i * 16 + rg4 + jj;
        xio[(size_t)row * 128 + col] += acc[i][j][jj] + bv;
      }
    }
  }
}

// ---------------------------------------------------------------- attention (32x32 MFMA flash)
#define VSTR2 296
__global__ __launch_bounds__(576)
void k_attn(const u16* __restrict__ qkv, const int* __restrict__ mask,
            u16* __restrict__ out) {
  int h = blockIdx.x, b = blockIdx.y;
  __shared__ __align__(16) u16 Klin[9 * 512];
  __shared__ __align__(16) u16 Vt[16 * VSTR2];
  __shared__ int part[4];
  const int tid = threadIdx.x;
  if (tid < 256) {
    int mv = (mask[b * SEQL + tid] != 0) ? 1 : 0;
    #pragma unroll
    for (int o = 32; o; o >>= 1) mv += __shfl_xor(mv, o);
    if ((tid & 63) == 0) part[tid >> 6] = mv;
  }
  {
    int r = tid >> 1, h2 = tid & 1;
    uint4 val = make_uint4(0, 0, 0, 0);
    if (r < NPOS)
      val = *(const uint4*)&qkv[((size_t)(b * NPOS + r)) * 384 + h * 16 + 128 + h2 * 8];
    *(uint4*)&Klin[(r >> 5) * 512 + h2 * 256 + (r & 31) * 8] = val;
  }
  if (tid < 288) {
    int r = tid;
    u16 tmp[16];
    if (r < NPOS) {
      const u16* vp = &qkv[((size_t)(b * NPOS + r)) * 384 + h * 16 + 256];
      *(uint4*)&tmp[0] = *(const uint4*)&vp[0];
      *(uint4*)&tmp[8] = *(const uint4*)&vp[8];
    } else {
      #pragma unroll
      for (int d = 0; d < 16; ++d) tmp[d] = 0;
    }
    #pragma unroll
    for (int d = 0; d < 16; ++d) Vt[d * VSTR2 + r] = tmp[d];
  }
  __syncthreads();
  const int nvalid = part[0] + part[1] + part[2] + part[3] + 3;
  const int ktiles = (nvalid + 31) >> 5;
  const int wave = tid >> 6, lane = tid & 63;
  const int q5 = lane & 31, hi = lane >> 5;
  const f32x16 zf = {};
  const int qt = wave;
  int qrow = qt * 32 + q5;
  int qr = (qrow < NPOS) ? qrow : (NPOS - 1);
  bf16x8 qf = *(const bf16x8*)&qkv[((size_t)(b * NPOS + qr)) * 384 + h * 16 + hi * 8];
  float m = -1e30f, l = 0.f;
  f32x16 acc = {};
  for (int kt = 0; kt < ktiles; ++kt) {
    bf16x8 kf = *(const bf16x8*)&Klin[kt * 512 + lane * 8];
    __builtin_amdgcn_s_setprio(1);
    f32x16 s4 = __builtin_amdgcn_mfma_f32_32x32x16_bf16(kf, qf, zf, 0, 0, 0);
    __builtin_amdgcn_s_setprio(0);
    float p[16];
    float tmax = -1e30f;
    #pragma unroll
    for (int r = 0; r < 16; ++r) {
      int kr = kt * 32 + (r & 3) + 8 * (r >> 2) + 4 * hi;
      float v = (kr < nvalid) ? s4[r] : -1e30f;
      p[r] = v;
      tmax = fmaxf(tmax, v);
    }
    tmax = fmaxf(tmax, __shfl_xor(tmax, 32));
    float mnew = fmaxf(m, tmax);
    float fac = exp2f(m - mnew);
    float tsum = 0.f;
    #pragma unroll
    for (int r = 0; r < 16; ++r) { p[r] = exp2f(p[r] - mnew); tsum += p[r]; }
    tsum += __shfl_xor(tsum, 32);
    l = l * fac + tsum;
    m = mnew;
    #pragma unroll
    for (int r = 0; r < 8; ++r) acc[r] *= fac;
    u32 w[8], xw[8];
    #pragma unroll
    for (int i = 0; i < 8; ++i)
      asm("v_cvt_pk_bf16_f32 %0, %1, %2" : "=v"(w[i]) : "v"(p[2 * i]), "v"(p[2 * i + 1]));
    #pragma unroll
    for (int i = 0; i < 8; ++i) xw[i] = (u32)__shfl_xor((int)w[i], 32);
    union { u32 u[4]; bf16x8 v; } f1, f2;
    if (hi) {
      f1.u[0] = xw[2]; f1.u[1] = xw[3]; f1.u[2] = w[2]; f1.u[3] = w[3];
      f2.u[0] = xw[6]; f2.u[1] = xw[7]; f2.u[2] = w[6]; f2.u[3] = w[7];
    } else {
      f1.u[0] = w[0]; f1.u[1] = w[1]; f1.u[2] = xw[0]; f1.u[3] = xw[1];
      f2.u[0] = w[4]; f2.u[1] = w[5]; f2.u[2] = xw[4]; f2.u[3] = xw[5];
    }
    bf16x8 vf0 = {}, vf1 = {};
    if (q5 < 16) {
      vf0 = *(const bf16x8*)&Vt[q5 * VSTR2 + kt * 32 + hi * 8];
      vf1 = *(const bf16x8*)&Vt[q5 * VSTR2 + kt * 32 + 16 + hi * 8];
    }
    __builtin_amdgcn_s_setprio(1);
    acc = __builtin_amdgcn_mfma_f32_32x32x16_bf16(vf0, f1.v, acc, 0, 0, 0);
    acc = __builtin_amdgcn_mfma_f32_32x32x16_bf16(vf1, f2.v, acc, 0, 0, 0);
    __builtin_amdgcn_s_setprio(0);
  }
  if (qrow < NPOS) {
    float linv = 1.f / l;
    u16* op = &out[((size_t)(b * NPOS + qrow)) * HD + h * 16];
    u32 w0 = (u32)f2bf(acc[0] * linv) | ((u32)f2bf(acc[1] * linv) << 16);
    u32 w1 = (u32)f2bf(acc[2] * linv) | ((u32)f2bf(acc[3] * linv) << 16);
    u32 w2 = (u32)f2bf(acc[4] * linv) | ((u32)f2bf(acc[5] * linv) << 16);
    u32 w3 = (u32)f2bf(acc[6] * linv) | ((u32)f2bf(acc[7] * linv) << 16);
    *(uint2*)&op[4 * hi] = make_uint2(w0, w1);
    *(uint2*)&op[8 + 4 * hi] = make_uint2(w2, w3);
  }
}

// ---------------------------------------------------------------- head
__global__ __launch_bounds__(128)
void k_head(const float* __restrict__ x, const float* __restrict__ bw,
            const float* __restrict__ bb, const float* __restrict__ cw,
            const float* __restrict__ cb, float* __restrict__ dout) {
  int b = blockIdx.x, n = threadIdx.x;
  __shared__ float lat[HD];
  __shared__ float redp[2], redss[2];
  float lv = x[((size_t)b * NPOS) * HD + n];
  lat[n] = lv;
  __syncthreads();
  float t = 0.f;
  for (int k = 0; k < HD; ++k) t += lat[k] * bw[k * HD + n];
  t += bb[n];
  t = fmaxf(t, 0.f);
  float p = t * cw[n];
  float ss = lv * lv;
  #pragma unroll
  for (int o = 32; o; o >>= 1) { p += __shfl_xor(p, o); ss += __shfl_xor(ss, o); }
  if ((n & 63) == 0) { redp[n >> 6] = p; redss[n >> 6] = ss; }
  __syncthreads();
  float psum = redp[0] + redp[1];
  float ssum = redss[0] + redss[1];
  if (n == 0) dout[b] = psum + cb[0];
  float nrm = fmaxf(sqrtf(ssum), 1e-12f);
  dout[256 + (size_t)b * HD + n] = lv / nrm;
}

// ---------------------------------------------------------------- launch
extern "C" void kernel_launch(void* const* d_in, const int* in_sizes, int n_in,
                              void* d_out, int out_size, void* d_ws, size_t ws_size,
                              hipStream_t stream) {
  const int* item_seq = (const int*)d_in[0];
  const int* action_seq = (const int*)d_in[1];
  const int* time_diff = (const int*)d_in[2];
  const int* mask = (const int*)d_in[3];
  const int* u_cv = (const int*)d_in[4];
  const int* u_cl = (const int*)d_in[5];
  const float* u_num = (const float*)d_in[6];
  const int* i_cv = (const int*)d_in[7];
  const int* i_cl = (const int*)d_in[8];
  const float* i_num = (const float*)d_in[9];
  const float* item_t = (const float*)d_in[10];
  const float* act_t = (const float*)d_in[11];
  const float* time_t = (const float*)d_in[12];
  const float* cat_t = (const float*)d_in[13];
  const float* num_W = (const float*)d_in[14];
  const float* gtok = (const float*)d_in[15];
  const float* ln1_g = (const float*)d_in[16];
  const float* ln1_b = (const float*)d_in[17];
  const float* qkv_w = (const float*)d_in[18];
  const float* qkv_b = (const float*)d_in[19];
  const float* out_w = (const float*)d_in[20];
  const float* out_b = (const float*)d_in[21];
  const float* w1 = (const float*)d_in[22];
  const float* b1 = (const float*)d_in[23];
  const float* w2 = (const float*)d_in[24];
  const float* b2 = (const float*)d_in[25];
  const float* ln2_g = (const float*)d_in[26];
  const float* ln2_b = (const float*)d_in[27];
  const float* bott_w = (const float*)d_in[28];
  const float* bott_b = (const float*)d_in[29];
  const float* cls_w = (const float*)d_in[30];
  const float* cls_b = (const float*)d_in[31];

  // workspace layout (bytes)
  const size_t off_x    = 0;                     // TTOK*128 f32  = 33,947,648
  const size_t off_src  = 33947648;              // TTOK*128 bf16 = 16,973,824 (LN1_0 out / attn out)
  const size_t off_qkv  = 50921472;              // TTOK*384 bf16 = 50,921,472
  const size_t off_h1   = 101842944;             // TTOK*512 bf16 = 67,895,296
  const size_t off_wT   = 169738240;             // 786,432 elems bf16 = 1,572,864
  const size_t need     = 171311104;
  if (ws_size < need) {
    fprintf(stderr, "kernel_launch: ws_size %zu < needed %zu\n", ws_size, need);
    return;
  }
  char* ws = (char*)d_ws;
  float* x    = (float*)(ws + off_x);
  u16* src    = (u16*)(ws + off_src);
  u16* qkvbuf = (u16*)(ws + off_qkv);
  u16* h1buf  = (u16*)(ws + off_h1);
  u16* wT     = (u16*)(ws + off_wT);
  u16* qkvT   = wT;                 // [4][384][128]
  u16* outT   = wT + 196608;        // [4][128][128]
  u16* w1T    = wT + 262144;        // [4][512][128]
  u16* w2T    = wT + 524288;        // [4][128][512]

  k_transpose_all<<<3072, 256, 0, stream>>>(qkv_w, out_w, w1, w2, wT);

  k_build<<<dim3(NPOS, BATCH), 128, 0, stream>>>(
      item_seq, action_seq, time_diff, u_cv, u_cl, u_num, i_cv, i_cl, i_num,
      item_t, act_t, time_t, cat_t, num_W, gtok, ln1_g, ln1_b, x, src);

  const int rt = TTOK / 128;  // 518
  // layer-0 QKV (q cols pre-scaled): src -> qkvbuf
  k_gemm_nres<3, 0, true><<<rt, 256, 0, stream>>>(src, qkvT, qkv_b, qkvbuf);

  for (int dd = 0; dd < DEPTH; ++dd) {
    // attention: qkvbuf -> src
    k_attn<<<dim3(NHEAD, BATCH), 576, 0, stream>>>(qkvbuf, mask, src);
    // proj + residual + LN2 + MLP1(gelu): src -> x, h1buf
    k_fused<128, 4, 1, false><<<rt, 256, 0, stream>>>(
        src, outT + dd * 16384, out_b + dd * HD, x,
        ln2_g + dd * HD, ln2_b + dd * HD,
        w1T + dd * 65536, b1 + dd * FF, h1buf);
    if (dd < 3) {
      // MLP2 + residual + LN1(next) + QKV(next): h1buf -> x, qkvbuf
      k_fused<512, 3, 0, true><<<rt, 256, 0, stream>>>(
          h1buf, w2T + dd * 65536, b2 + dd * HD, x,
          ln1_g + (dd + 1) * HD, ln1_b + (dd + 1) * HD,
          qkvT + (dd + 1) * 49152, qkv_b + (dd + 1) * 384, qkvbuf);
    } else {
      // last MLP2: residual only
      k_gemm_res<<<rt, 256, 0, stream>>>(h1buf, w2T + dd * 65536, b2 + dd * HD, x, 512);
    }
  }

  k_head<<<BATCH, 128, 0, stream>>>(x, bott_w, bott_b, cls_w, cls_b, (float*)d_out);
}

// Round 12
// 722.229 us; speedup vs baseline: 1.4091x; 1.4091x over previous
//
#include <hip/hip_runtime.h>
#include <cstdio>

// Problem constants
#define BATCH 256
#define SEQL 256
#define NPOS 259            // 3 + SEQL
#define TTOK (BATCH*NPOS)   // 66304 = 1036 * 64
#define HD 128
#define NHEAD 8
#define FF 512
#define DEPTH 4
#define CVOC 50001

typedef unsigned short u16;
typedef unsigned int u32;
typedef __bf16 bf16x8 __attribute__((ext_vector_type(8)));
typedef float f32x4 __attribute__((ext_vector_type(4)));
typedef float f32x16 __attribute__((ext_vector_type(16)));

typedef const __attribute__((address_space(1))) u32 gas_u32;
typedef __attribute__((address_space(3))) u32 las_u32;
#define GLOAD16(gptr, lptr) \
  __builtin_amdgcn_global_load_lds((gas_u32*)(gptr), (las_u32*)(lptr), 16, 0, 0)

// SCALE * log2(e): q pre-scaled so attention softmax can use native exp2
#define QSCALE 0.36067376022224085f

__device__ __forceinline__ u16 f2bf(float f) {
  u32 i = __float_as_uint(f);
  u32 r = (i + 0x7FFFu + ((i >> 16) & 1u)) >> 16;   // RNE
  return (u16)r;
}

// ---------------------------------------------------------------- merged transpose + downcast
__global__ void k_transpose_all(const float* __restrict__ qkv_w, const float* __restrict__ out_w,
                                const float* __restrict__ w1, const float* __restrict__ w2,
                                u16* __restrict__ wT) {
  int idx = blockIdx.x * 256 + threadIdx.x;
  const float* in; int K, N, local;
  if (idx < 196608)      { in = qkv_w; K = 128; N = 384; local = idx; }
  else if (idx < 262144) { in = out_w; K = 128; N = 128; local = idx - 196608; }
  else if (idx < 524288) { in = w1;    K = 128; N = 512; local = idx - 262144; }
  else if (idx < 786432) { in = w2;    K = 512; N = 128; local = idx - 524288; }
  else return;
  int k = local % K; int rem = local / K; int n = rem % N; int d = rem / N;
  wT[idx] = f2bf(in[(d * K + k) * N + n]);
}

// ---------------------------------------------------------------- build x (+ fused layer-0 LN1)
__global__ __launch_bounds__(128)
void k_build(const int* __restrict__ item_seq, const int* __restrict__ act_seq,
             const int* __restrict__ tdiff,
             const int* __restrict__ ucv, const int* __restrict__ ucl, const float* __restrict__ unum,
             const int* __restrict__ icv, const int* __restrict__ icl, const float* __restrict__ inum,
             const float* __restrict__ item_t, const float* __restrict__ act_t,
             const float* __restrict__ time_t, const float* __restrict__ cat_t,
             const float* __restrict__ numW, const float* __restrict__ gtok,
             const float* __restrict__ g, const float* __restrict__ be,
             float* __restrict__ x, u16* __restrict__ src) {
  int pos = blockIdx.x, b = blockIdx.y, h = threadIdx.x;
  float v;
  if (pos == 0) {
    v = gtok[h];
  } else if (pos <= 2) {
    const int* cv = (pos == 1) ? ucv : icv;
    const int* cl = (pos == 1) ? ucl : icl;
    const float* nm = (pos == 1) ? unum : inum;
    float acc = 0.f;
    for (int f = 0; f < 8; ++f) {
      float s = 0.f;
      for (int k = 0; k < 8; ++k) {
        int idx = cv[(b * 8 + f) * 8 + k];
        s += cat_t[((size_t)f * CVOC + idx) * HD + h];
      }
      acc += s / (float)cl[b * 8 + f];
    }
    for (int f = 0; f < 4; ++f)
      for (int d = 0; d < 32; ++d)
        acc += nm[(b * 4 + f) * 32 + d] * numW[(f * 32 + d) * HD + h];
    v = acc * (1.f / 12.f);
  } else {
    int l = pos - 3;
    v = item_t[(size_t)item_seq[b * SEQL + l] * HD + h]
      + act_t[(size_t)act_seq[b * SEQL + l] * HD + h]
      + time_t[(size_t)tdiff[b * SEQL + l] * HD + h];
  }
  size_t t = (size_t)b * NPOS + pos;
  x[t * HD + h] = v;
  __shared__ float red[2][2];
  float s = v, s2 = v * v;
  #pragma unroll
  for (int o = 32; o; o >>= 1) { s += __shfl_xor(s, o); s2 += __shfl_xor(s2, o); }
  if ((h & 63) == 0) { red[h >> 6][0] = s; red[h >> 6][1] = s2; }
  __syncthreads();
  float S = red[0][0] + red[1][0], S2 = red[0][1] + red[1][1];
  float mean = S * (1.f / HD);
  float rstd = rsqrtf(S2 * (1.f / HD) - mean * mean + 1e-5f);
  src[t * HD + h] = f2bf((v - mean) * rstd * g[h] + be[h]);
}

// ---------------------------------------------------------------- GEMM, A-resident multi-N, 64-row tiles
// Y[64-row stripe x NCH*128] = act(X @ W + bias); WT[N][128] bf16, K=128.
// A (64x128) staged once (16KB LDS); per n-chunk, B staged 8KB/k-step.
// Grid: TTOK/64 = 1036 blocks (~4/CU) for latency hiding. Waves 2x2: 32 rows x 64 cols each.
template <int NCH, int ACT, bool QS>
__global__ __launch_bounds__(256)
void k_gemm_nres(const u16* __restrict__ X, const u16* __restrict__ WT,
                 const float* __restrict__ bias, u16* __restrict__ outp) {
  const int K = 128, N = NCH * 128;
  __shared__ __align__(16) u16 lA[4][64 * 32];
  __shared__ __align__(16) u16 lB[128 * 32];
  const int tid = threadIdx.x;
  const int wave = tid >> 6, lane = tid & 63;
  const int row0 = blockIdx.x * 64;
  const int wr = (wave >> 1) * 32, wc = (wave & 1) * 64;
  const int sr = lane >> 2;
  const int sc = ((lane & 3) ^ ((lane >> 3) & 3)) << 3;
  const int q = lane & 15;
  const int cg = lane >> 4;
  const int rdoff = ((cg ^ ((q >> 1) & 3)) << 3);
  // stage full A: wave w stages rows [16w,16w+16) for each k-subtile
  #pragma unroll
  for (int kt = 0; kt < 4; ++kt)
    GLOAD16(X + (size_t)(row0 + wave * 16 + sr) * K + kt * 32 + sc, &lA[kt][wave * 512]);
  const u16* gB0 = WT + (size_t)(wave * 16 + sr) * K + sc;
  const u16* gB1 = WT + (size_t)(64 + wave * 16 + sr) * K + sc;
  u16* lB0 = &lB[wave * 512];
  u16* lB1 = &lB[2048 + wave * 512];
  for (int nc = 0; nc < NCH; ++nc) {
    const size_t nbase = (size_t)nc * 128 * K;
    f32x4 acc[2][4] = {};
    for (int k0 = 0; k0 < K; k0 += 32) {
      __syncthreads();
      GLOAD16(gB0 + nbase + k0, lB0);
      GLOAD16(gB1 + nbase + k0, lB1);
      __syncthreads();
      const int kt = k0 >> 5;
      bf16x8 af[2], bf[4];
      #pragma unroll
      for (int i = 0; i < 2; ++i)
        af[i] = *(const bf16x8*)&lA[kt][(wr + i * 16 + q) * 32 + rdoff];
      #pragma unroll
      for (int j = 0; j < 4; ++j)
        bf[j] = *(const bf16x8*)&lB[(wc + j * 16 + q) * 32 + rdoff];
      #pragma unroll
      for (int i = 0; i < 2; ++i)
        #pragma unroll
        for (int j = 0; j < 4; ++j)
          acc[i][j] = __builtin_amdgcn_mfma_f32_16x16x32_bf16(af[i], bf[j], acc[i][j], 0, 0, 0);
    }
    const int rg4 = cg * 4;
    const float scl = (QS && nc == 0) ? QSCALE : 1.f;
    #pragma unroll
    for (int i = 0; i < 2; ++i) {
      #pragma unroll
      for (int j = 0; j < 4; ++j) {
        int col = nc * 128 + wc + j * 16 + q;
        float bv = bias[col];
        #pragma unroll
        for (int jj = 0; jj < 4; ++jj) {
          int row = row0 + wr + i * 16 + rg4 + jj;
          float v = acc[i][j][jj] + bv;
          if (ACT == 1) v = 0.5f * v * (1.f + erff(v * 0.70710678118654752f));
          if (QS) v *= scl;
          outp[(size_t)row * N + col] = f2bf(v);
        }
      }
    }
  }
}

// ---------------------------------------------------------------- residual GEMM + fused LN, 64-row tiles
// xnew = xio + X@WT + bias (written back); srcout = LN(xnew; g,be) bf16.
// 64 rows x 128 cols per block; all cols in-block so LN stats stay in-block.
__global__ __launch_bounds__(256)
void k_gemm_ln(const u16* __restrict__ X, const u16* __restrict__ WT,
               const float* __restrict__ bias, float* __restrict__ xio,
               const float* __restrict__ g, const float* __restrict__ be,
               u16* __restrict__ srcout, int K) {
  __shared__ __align__(16) u16 lA[64 * 32];
  __shared__ __align__(16) u16 lB[128 * 32];
  __shared__ float part[64][2][2];
  const int tid = threadIdx.x;
  const int wave = tid >> 6, lane = tid & 63;
  const int row0 = blockIdx.x * 64;
  const int wr = (wave >> 1) * 32, wc = (wave & 1) * 64;
  const int whalf = wave & 1;
  const int sr = lane >> 2;
  const int sc = ((lane & 3) ^ ((lane >> 3) & 3)) << 3;
  const u16* gA = X + (size_t)(row0 + wave * 16 + sr) * K + sc;
  const u16* gB0 = WT + (size_t)(wave * 16 + sr) * K + sc;
  const u16* gB1 = WT + (size_t)(64 + wave * 16 + sr) * K + sc;
  u16* lA0 = &lA[wave * 512];
  u16* lB0 = &lB[wave * 512];
  u16* lB1 = &lB[2048 + wave * 512];
  const int q = lane & 15;
  const int cg = lane >> 4;
  const int rdoff = ((cg ^ ((q >> 1) & 3)) << 3);
  f32x4 acc[2][4] = {};
  for (int k0 = 0; k0 < K; k0 += 32) {
    __syncthreads();
    GLOAD16(gA + k0, lA0);
    GLOAD16(gB0 + k0, lB0);
    GLOAD16(gB1 + k0, lB1);
    __syncthreads();
    bf16x8 af[2], bf[4];
    #pragma unroll
    for (int i = 0; i < 2; ++i)
      af[i] = *(const bf16x8*)&lA[(wr + i * 16 + q) * 32 + rdoff];
    #pragma unroll
    for (int j = 0; j < 4; ++j)
      bf[j] = *(const bf16x8*)&lB[(wc + j * 16 + q) * 32 + rdoff];
    #pragma unroll
    for (int i = 0; i < 2; ++i)
      #pragma unroll
      for (int j = 0; j < 4; ++j)
        acc[i][j] = __builtin_amdgcn_mfma_f32_16x16x32_bf16(af[i], bf[j], acc[i][j], 0, 0, 0);
  }
  const int rg4 = cg * 4;
  float ps[2][4], ps2[2][4];
  #pragma unroll
  for (int i = 0; i < 2; ++i)
    #pragma unroll
    for (int jj = 0; jj < 4; ++jj) { ps[i][jj] = 0.f; ps2[i][jj] = 0.f; }
  #pragma unroll
  for (int i = 0; i < 2; ++i) {
    #pragma unroll
    for (int j = 0; j < 4; ++j) {
      int col = wc + j * 16 + q;
      float bv = bias[col];
      #pragma unroll
      for (int jj = 0; jj < 4; ++jj) {
        int row = row0 + wr + i * 16 + rg4 + jj;
        float xv = xio[(size_t)row * 128 + col] + acc[i][j][jj] + bv;
        acc[i][j][jj] = xv;
        ps[i][jj] += xv;
        ps2[i][jj] += xv * xv;
      }
    }
  }
  #pragma unroll
  for (int o = 1; o < 16; o <<= 1) {
    #pragma unroll
    for (int i = 0; i < 2; ++i)
      #pragma unroll
      for (int jj = 0; jj < 4; ++jj) {
        ps[i][jj]  += __shfl_xor(ps[i][jj], o);
        ps2[i][jj] += __shfl_xor(ps2[i][jj], o);
      }
  }
  if (q == 0) {
    #pragma unroll
    for (int i = 0; i < 2; ++i)
      #pragma unroll
      for (int jj = 0; jj < 4; ++jj) {
        int rl = wr + i * 16 + rg4 + jj;
        part[rl][whalf][0] = ps[i][jj];
        part[rl][whalf][1] = ps2[i][jj];
      }
  }
  __syncthreads();
  #pragma unroll
  for (int i = 0; i < 2; ++i) {
    #pragma unroll
    for (int jj = 0; jj < 4; ++jj) {
      int rl = wr + i * 16 + rg4 + jj;
      float S  = part[rl][0][0] + part[rl][1][0];
      float S2 = part[rl][0][1] + part[rl][1][1];
      float mean = S * (1.f / 128.f);
      float rstd = rsqrtf(S2 * (1.f / 128.f) - mean * mean + 1e-5f);
      int row = row0 + rl;
      #pragma unroll
      for (int j = 0; j < 4; ++j) {
        int col = wc + j * 16 + q;
        float xv = acc[i][j][jj];
        xio[(size_t)row * 128 + col] = xv;
        srcout[(size_t)row * 128 + col] = f2bf((xv - mean) * rstd * g[col] + be[col]);
      }
    }
  }
}

// ---------------------------------------------------------------- attention (32x32 MFMA flash)
// grid (BATCH, NHEAD): same-b blocks land on the same XCD (index%8 = b%8) -> qkv L2 locality.
// 576 threads = 9 waves, one q-tile per wave. Defer-max (THR=8, exp2 domain).
#define VSTR2 296
__global__ __launch_bounds__(576)
void k_attn(const u16* __restrict__ qkv, const int* __restrict__ mask,
            u16* __restrict__ out) {
  int b = blockIdx.x, h = blockIdx.y;
  __shared__ __align__(16) u16 Klin[9 * 512];
  __shared__ __align__(16) u16 Vt[16 * VSTR2];
  __shared__ int part[4];
  const int tid = threadIdx.x;
  if (tid < 256) {
    int mv = (mask[b * SEQL + tid] != 0) ? 1 : 0;
    #pragma unroll
    for (int o = 32; o; o >>= 1) mv += __shfl_xor(mv, o);
    if ((tid & 63) == 0) part[tid >> 6] = mv;
  }
  {
    int r = tid >> 1, h2 = tid & 1;
    uint4 val = make_uint4(0, 0, 0, 0);
    if (r < NPOS)
      val = *(const uint4*)&qkv[((size_t)(b * NPOS + r)) * 384 + h * 16 + 128 + h2 * 8];
    *(uint4*)&Klin[(r >> 5) * 512 + h2 * 256 + (r & 31) * 8] = val;
  }
  if (tid < 288) {
    int r = tid;
    u16 tmp[16];
    if (r < NPOS) {
      const u16* vp = &qkv[((size_t)(b * NPOS + r)) * 384 + h * 16 + 256];
      *(uint4*)&tmp[0] = *(const uint4*)&vp[0];
      *(uint4*)&tmp[8] = *(const uint4*)&vp[8];
    } else {
      #pragma unroll
      for (int d = 0; d < 16; ++d) tmp[d] = 0;
    }
    #pragma unroll
    for (int d = 0; d < 16; ++d) Vt[d * VSTR2 + r] = tmp[d];
  }
  __syncthreads();
  const int nvalid = part[0] + part[1] + part[2] + part[3] + 3;
  const int ktiles = (nvalid + 31) >> 5;
  const int wave = tid >> 6, lane = tid & 63;
  const int q5 = lane & 31, hi = lane >> 5;
  const f32x16 zf = {};
  const int qt = wave;
  int qrow = qt * 32 + q5;
  int qr = (qrow < NPOS) ? qrow : (NPOS - 1);
  bf16x8 qf = *(const bf16x8*)&qkv[((size_t)(b * NPOS + qr)) * 384 + h * 16 + hi * 8];
  float m = -1e30f, l = 0.f;
  f32x16 acc = {};
  for (int kt = 0; kt < ktiles; ++kt) {
    bf16x8 kf = *(const bf16x8*)&Klin[kt * 512 + lane * 8];
    __builtin_amdgcn_s_setprio(1);
    f32x16 s4 = __builtin_amdgcn_mfma_f32_32x32x16_bf16(kf, qf, zf, 0, 0, 0);
    __builtin_amdgcn_s_setprio(0);
    float p[16];
    float tmax = -1e30f;
    #pragma unroll
    for (int r = 0; r < 16; ++r) {
      int kr = kt * 32 + (r & 3) + 8 * (r >> 2) + 4 * hi;
      float v = (kr < nvalid) ? s4[r] : -1e30f;
      p[r] = v;
      tmax = fmaxf(tmax, v);
    }
    tmax = fmaxf(tmax, __shfl_xor(tmax, 32));
    // defer-max: skip rescale when max grew by <= 8 (exp2 domain; P bounded by 2^8, fp32 headroom)
    bool defer = __all(tmax <= m + 8.f);
    float mnew = defer ? m : fmaxf(m, tmax);
    float fac = defer ? 1.f : exp2f(m - mnew);
    float tsum = 0.f;
    #pragma unroll
    for (int r = 0; r < 16; ++r) { p[r] = exp2f(p[r] - mnew); tsum += p[r]; }
    tsum += __shfl_xor(tsum, 32);
    l = l * fac + tsum;
    m = mnew;
    if (!defer) {
      #pragma unroll
      for (int r = 0; r < 8; ++r) acc[r] *= fac;
    }
    u32 w[8], xw[8];
    #pragma unroll
    for (int i = 0; i < 8; ++i)
      asm("v_cvt_pk_bf16_f32 %0, %1, %2" : "=v"(w[i]) : "v"(p[2 * i]), "v"(p[2 * i + 1]));
    #pragma unroll
    for (int i = 0; i < 8; ++i) xw[i] = (u32)__shfl_xor((int)w[i], 32);
    union { u32 u[4]; bf16x8 v; } f1, f2;
    if (hi) {
      f1.u[0] = xw[2]; f1.u[1] = xw[3]; f1.u[2] = w[2]; f1.u[3] = w[3];
      f2.u[0] = xw[6]; f2.u[1] = xw[7]; f2.u[2] = w[6]; f2.u[3] = w[7];
    } else {
      f1.u[0] = w[0]; f1.u[1] = w[1]; f1.u[2] = xw[0]; f1.u[3] = xw[1];
      f2.u[0] = w[4]; f2.u[1] = w[5]; f2.u[2] = xw[4]; f2.u[3] = xw[5];
    }
    bf16x8 vf0 = {}, vf1 = {};
    if (q5 < 16) {
      vf0 = *(const bf16x8*)&Vt[q5 * VSTR2 + kt * 32 + hi * 8];
      vf1 = *(const bf16x8*)&Vt[q5 * VSTR2 + kt * 32 + 16 + hi * 8];
    }
    __builtin_amdgcn_s_setprio(1);
    acc = __builtin_amdgcn_mfma_f32_32x32x16_bf16(vf0, f1.v, acc, 0, 0, 0);
    acc = __builtin_amdgcn_mfma_f32_32x32x16_bf16(vf1, f2.v, acc, 0, 0, 0);
    __builtin_amdgcn_s_setprio(0);
  }
  if (qrow < NPOS) {
    float linv = 1.f / l;
    u16* op = &out[((size_t)(b * NPOS + qrow)) * HD + h * 16];
    u32 w0 = (u32)f2bf(acc[0] * linv) | ((u32)f2bf(acc[1] * linv) << 16);
    u32 w1 = (u32)f2bf(acc[2] * linv) | ((u32)f2bf(acc[3] * linv) << 16);
    u32 w2 = (u32)f2bf(acc[4] * linv) | ((u32)f2bf(acc[5] * linv) << 16);
    u32 w3 = (u32)f2bf(acc[6] * linv) | ((u32)f2bf(acc[7] * linv) << 16);
    *(uint2*)&op[4 * hi] = make_uint2(w0, w1);
    *(uint2*)&op[8 + 4 * hi] = make_uint2(w2, w3);
  }
}

// ---------------------------------------------------------------- head
__global__ __launch_bounds__(128)
void k_head(const float* __restrict__ x, const float* __restrict__ bw,
            const float* __restrict__ bb, const float* __restrict__ cw,
            const float* __restrict__ cb, float* __restrict__ dout) {
  int b = blockIdx.x, n = threadIdx.x;
  __shared__ float lat[HD];
  __shared__ float redp[2], redss[2];
  float lv = x[((size_t)b * NPOS) * HD + n];
  lat[n] = lv;
  __syncthreads();
  float t = 0.f;
  for (int k = 0; k < HD; ++k) t += lat[k] * bw[k * HD + n];
  t += bb[n];
  t = fmaxf(t, 0.f);
  float p = t * cw[n];
  float ss = lv * lv;
  #pragma unroll
  for (int o = 32; o; o >>= 1) { p += __shfl_xor(p, o); ss += __shfl_xor(ss, o); }
  if ((n & 63) == 0) { redp[n >> 6] = p; redss[n >> 6] = ss; }
  __syncthreads();
  float psum = redp[0] + redp[1];
  float ssum = redss[0] + redss[1];
  if (n == 0) dout[b] = psum + cb[0];
  float nrm = fmaxf(sqrtf(ssum), 1e-12f);
  dout[256 + (size_t)b * HD + n] = lv / nrm;
}

// ---------------------------------------------------------------- launch
extern "C" void kernel_launch(void* const* d_in, const int* in_sizes, int n_in,
                              void* d_out, int out_size, void* d_ws, size_t ws_size,
                              hipStream_t stream) {
  const int* item_seq = (const int*)d_in[0];
  const int* action_seq = (const int*)d_in[1];
  const int* time_diff = (const int*)d_in[2];
  const int* mask = (const int*)d_in[3];
  const int* u_cv = (const int*)d_in[4];
  const int* u_cl = (const int*)d_in[5];
  const float* u_num = (const float*)d_in[6];
  const int* i_cv = (const int*)d_in[7];
  const int* i_cl = (const int*)d_in[8];
  const float* i_num = (const float*)d_in[9];
  const float* item_t = (const float*)d_in[10];
  const float* act_t = (const float*)d_in[11];
  const float* time_t = (const float*)d_in[12];
  const float* cat_t = (const float*)d_in[13];
  const float* num_W = (const float*)d_in[14];
  const float* gtok = (const float*)d_in[15];
  const float* ln1_g = (const float*)d_in[16];
  const float* ln1_b = (const float*)d_in[17];
  const float* qkv_w = (const float*)d_in[18];
  const float* qkv_b = (const float*)d_in[19];
  const float* out_w = (const float*)d_in[20];
  const float* out_b = (const float*)d_in[21];
  const float* w1 = (const float*)d_in[22];
  const float* b1 = (const float*)d_in[23];
  const float* w2 = (const float*)d_in[24];
  const float* b2 = (const float*)d_in[25];
  const float* ln2_g = (const float*)d_in[26];
  const float* ln2_b = (const float*)d_in[27];
  const float* bott_w = (const float*)d_in[28];
  const float* bott_b = (const float*)d_in[29];
  const float* cls_w = (const float*)d_in[30];
  const float* cls_b = (const float*)d_in[31];

  // workspace layout (bytes)
  const size_t off_x   = 0;                    // TTOK*128 f32  = 33,947,648
  const size_t off_src = 33947648;             // TTOK*128 bf16 = 16,973,824
  const size_t off_big = 50921472;             // TTOK*512 bf16 = 67,895,296
  const size_t off_wT  = 118816768;            // 786,432 elems bf16
  const size_t need    = 120389632;
  if (ws_size < need) {
    fprintf(stderr, "kernel_launch: ws_size %zu < needed %zu\n", ws_size, need);
    return;
  }
  char* ws = (char*)d_ws;
  float* x   = (float*)(ws + off_x);
  u16* src   = (u16*)(ws + off_src);
  u16* big   = (u16*)(ws + off_big);
  u16* wT    = (u16*)(ws + off_wT);
  u16* qkvT  = wT;                 // [4][384][128]
  u16* outT  = wT + 196608;        // [4][128][128]
  u16* w1T   = wT + 262144;        // [4][512][128]
  u16* w2T   = wT + 524288;        // [4][128][512]

  k_transpose_all<<<3072, 256, 0, stream>>>(qkv_w, out_w, w1, w2, wT);

  k_build<<<dim3(NPOS, BATCH), 128, 0, stream>>>(
      item_seq, action_seq, time_diff, u_cv, u_cl, u_num, i_cv, i_cl, i_num,
      item_t, act_t, time_t, cat_t, num_W, gtok, ln1_g, ln1_b, x, src);

  const int rt = TTOK / 64;  // 1036
  for (int dd = 0; dd < DEPTH; ++dd) {
    // QKV (q cols pre-scaled by QSCALE): src -> big
    k_gemm_nres<3, 0, true><<<rt, 256, 0, stream>>>(
        src, qkvT + dd * 49152, qkv_b + dd * 384, big);
    // attention: big -> src
    k_attn<<<dim3(BATCH, NHEAD), 576, 0, stream>>>(big, mask, src);
    // proj + residual + fused LN2: src(attn) -> x, src(LN2 out)
    k_gemm_ln<<<rt, 256, 0, stream>>>(
        src, outT + dd * 16384, out_b + dd * HD, x,
        ln2_g + dd * HD, ln2_b + dd * HD, src, 128);
    // MLP1 (gelu): src -> big
    k_gemm_nres<4, 1, false><<<rt, 256, 0, stream>>>(
        src, w1T + dd * 65536, b1 + dd * FF, big);
    // MLP2 + residual + fused LN1 of next layer: big -> x, src
    const float* ng = (dd < 3) ? (ln1_g + (dd + 1) * HD) : (ln1_g + dd * HD);
    const float* nb = (dd < 3) ? (ln1_b + (dd + 1) * HD) : (ln1_b + dd * HD);
    k_gemm_ln<<<rt, 256, 0, stream>>>(
        big, w2T + dd * 65536, b2 + dd * HD, x, ng, nb, src, 512);
  }

  k_head<<<BATCH, 128, 0, stream>>>(x, bott_w, bott_b, cls_w, cls_b, (float*)d_out);
}

// Round 13
// 704.849 us; speedup vs baseline: 1.4439x; 1.0247x over previous
//
#include <hip/hip_runtime.h>
#include <cstdio>

// Problem constants
#define BATCH 256
#define SEQL 256
#define NPOS 259            // 3 + SEQL
#define TTOK (BATCH*NPOS)   // 66304 = 1036 * 64
#define HD 128
#define NHEAD 8
#define FF 512
#define DEPTH 4
#define CVOC 50001

typedef unsigned short u16;
typedef unsigned int u32;
typedef __bf16 bf16x8 __attribute__((ext_vector_type(8)));
typedef float f32x4 __attribute__((ext_vector_type(4)));
typedef float f32x16 __attribute__((ext_vector_type(16)));

typedef const __attribute__((address_space(1))) u32 gas_u32;
typedef __attribute__((address_space(3))) u32 las_u32;
#define GLOAD16(gptr, lptr) \
  __builtin_amdgcn_global_load_lds((gas_u32*)(gptr), (las_u32*)(lptr), 16, 0, 0)

// SCALE * log2(e): q pre-scaled so attention softmax can use native exp2
#define QSCALE 0.36067376022224085f

__device__ __forceinline__ u16 f2bf(float f) {
  u32 i = __float_as_uint(f);
  u32 r = (i + 0x7FFFu + ((i >> 16) & 1u)) >> 16;   // RNE
  return (u16)r;
}
__device__ __forceinline__ float bf2f(u16 u) {
  return __uint_as_float(((u32)u) << 16);
}

// ---------------------------------------------------------------- merged transpose + downcast
__global__ void k_transpose_all(const float* __restrict__ qkv_w, const float* __restrict__ out_w,
                                const float* __restrict__ w1, const float* __restrict__ w2,
                                u16* __restrict__ wT) {
  int idx = blockIdx.x * 256 + threadIdx.x;
  const float* in; int K, N, local;
  if (idx < 196608)      { in = qkv_w; K = 128; N = 384; local = idx; }
  else if (idx < 262144) { in = out_w; K = 128; N = 128; local = idx - 196608; }
  else if (idx < 524288) { in = w1;    K = 128; N = 512; local = idx - 262144; }
  else if (idx < 786432) { in = w2;    K = 512; N = 128; local = idx - 524288; }
  else return;
  int k = local % K; int rem = local / K; int n = rem % N; int d = rem / N;
  wT[idx] = f2bf(in[(d * K + k) * N + n]);
}

// ---------------------------------------------------------------- build x (+ fused layer-0 LN1)
// x stored bf16 (residual stream); LN computed from unrounded fp32 v.
__global__ __launch_bounds__(128)
void k_build(const int* __restrict__ item_seq, const int* __restrict__ act_seq,
             const int* __restrict__ tdiff,
             const int* __restrict__ ucv, const int* __restrict__ ucl, const float* __restrict__ unum,
             const int* __restrict__ icv, const int* __restrict__ icl, const float* __restrict__ inum,
             const float* __restrict__ item_t, const float* __restrict__ act_t,
             const float* __restrict__ time_t, const float* __restrict__ cat_t,
             const float* __restrict__ numW, const float* __restrict__ gtok,
             const float* __restrict__ g, const float* __restrict__ be,
             u16* __restrict__ x, u16* __restrict__ src) {
  int pos = blockIdx.x, b = blockIdx.y, h = threadIdx.x;
  float v;
  if (pos == 0) {
    v = gtok[h];
  } else if (pos <= 2) {
    const int* cv = (pos == 1) ? ucv : icv;
    const int* cl = (pos == 1) ? ucl : icl;
    const float* nm = (pos == 1) ? unum : inum;
    float acc = 0.f;
    for (int f = 0; f < 8; ++f) {
      float s = 0.f;
      for (int k = 0; k < 8; ++k) {
        int idx = cv[(b * 8 + f) * 8 + k];
        s += cat_t[((size_t)f * CVOC + idx) * HD + h];
      }
      acc += s / (float)cl[b * 8 + f];
    }
    for (int f = 0; f < 4; ++f)
      for (int d = 0; d < 32; ++d)
        acc += nm[(b * 4 + f) * 32 + d] * numW[(f * 32 + d) * HD + h];
    v = acc * (1.f / 12.f);
  } else {
    int l = pos - 3;
    v = item_t[(size_t)item_seq[b * SEQL + l] * HD + h]
      + act_t[(size_t)act_seq[b * SEQL + l] * HD + h]
      + time_t[(size_t)tdiff[b * SEQL + l] * HD + h];
  }
  size_t t = (size_t)b * NPOS + pos;
  x[t * HD + h] = f2bf(v);
  __shared__ float red[2][2];
  float s = v, s2 = v * v;
  #pragma unroll
  for (int o = 32; o; o >>= 1) { s += __shfl_xor(s, o); s2 += __shfl_xor(s2, o); }
  if ((h & 63) == 0) { red[h >> 6][0] = s; red[h >> 6][1] = s2; }
  __syncthreads();
  float S = red[0][0] + red[1][0], S2 = red[0][1] + red[1][1];
  float mean = S * (1.f / HD);
  float rstd = rsqrtf(S2 * (1.f / HD) - mean * mean + 1e-5f);
  src[t * HD + h] = f2bf((v - mean) * rstd * g[h] + be[h]);
}

// ---------------------------------------------------------------- GEMM, A-resident multi-N, 64-row tiles
template <int NCH, int ACT, bool QS>
__global__ __launch_bounds__(256)
void k_gemm_nres(const u16* __restrict__ X, const u16* __restrict__ WT,
                 const float* __restrict__ bias, u16* __restrict__ outp) {
  const int K = 128, N = NCH * 128;
  __shared__ __align__(16) u16 lA[4][64 * 32];
  __shared__ __align__(16) u16 lB[128 * 32];
  const int tid = threadIdx.x;
  const int wave = tid >> 6, lane = tid & 63;
  const int row0 = blockIdx.x * 64;
  const int wr = (wave >> 1) * 32, wc = (wave & 1) * 64;
  const int sr = lane >> 2;
  const int sc = ((lane & 3) ^ ((lane >> 3) & 3)) << 3;
  const int q = lane & 15;
  const int cg = lane >> 4;
  const int rdoff = ((cg ^ ((q >> 1) & 3)) << 3);
  #pragma unroll
  for (int kt = 0; kt < 4; ++kt)
    GLOAD16(X + (size_t)(row0 + wave * 16 + sr) * K + kt * 32 + sc, &lA[kt][wave * 512]);
  const u16* gB0 = WT + (size_t)(wave * 16 + sr) * K + sc;
  const u16* gB1 = WT + (size_t)(64 + wave * 16 + sr) * K + sc;
  u16* lB0 = &lB[wave * 512];
  u16* lB1 = &lB[2048 + wave * 512];
  for (int nc = 0; nc < NCH; ++nc) {
    const size_t nbase = (size_t)nc * 128 * K;
    f32x4 acc[2][4] = {};
    for (int k0 = 0; k0 < K; k0 += 32) {
      __syncthreads();
      GLOAD16(gB0 + nbase + k0, lB0);
      GLOAD16(gB1 + nbase + k0, lB1);
      __syncthreads();
      const int kt = k0 >> 5;
      bf16x8 af[2], bf[4];
      #pragma unroll
      for (int i = 0; i < 2; ++i)
        af[i] = *(const bf16x8*)&lA[kt][(wr + i * 16 + q) * 32 + rdoff];
      #pragma unroll
      for (int j = 0; j < 4; ++j)
        bf[j] = *(const bf16x8*)&lB[(wc + j * 16 + q) * 32 + rdoff];
      #pragma unroll
      for (int i = 0; i < 2; ++i)
        #pragma unroll
        for (int j = 0; j < 4; ++j)
          acc[i][j] = __builtin_amdgcn_mfma_f32_16x16x32_bf16(af[i], bf[j], acc[i][j], 0, 0, 0);
    }
    const int rg4 = cg * 4;
    const float scl = (QS && nc == 0) ? QSCALE : 1.f;
    #pragma unroll
    for (int i = 0; i < 2; ++i) {
      #pragma unroll
      for (int j = 0; j < 4; ++j) {
        int col = nc * 128 + wc + j * 16 + q;
        float bv = bias[col];
        #pragma unroll
        for (int jj = 0; jj < 4; ++jj) {
          int row = row0 + wr + i * 16 + rg4 + jj;
          float v = acc[i][j][jj] + bv;
          if (ACT == 1) v = 0.5f * v * (1.f + erff(v * 0.70710678118654752f));
          if (QS) v *= scl;
          outp[(size_t)row * N + col] = f2bf(v);
        }
      }
    }
  }
}

// ---------------------------------------------------------------- residual GEMM + fused LN, 64-row tiles
// xnew = bf2f(xio) + X@WT + bias; xio (bf16) written back; srcout = LN(xnew) bf16.
// LN stats computed on unrounded fp32 xnew.
__global__ __launch_bounds__(256)
void k_gemm_ln(const u16* __restrict__ X, const u16* __restrict__ WT,
               const float* __restrict__ bias, u16* __restrict__ xio,
               const float* __restrict__ g, const float* __restrict__ be,
               u16* __restrict__ srcout, int K) {
  __shared__ __align__(16) u16 lA[64 * 32];
  __shared__ __align__(16) u16 lB[128 * 32];
  __shared__ float part[64][2][2];
  const int tid = threadIdx.x;
  const int wave = tid >> 6, lane = tid & 63;
  const int row0 = blockIdx.x * 64;
  const int wr = (wave >> 1) * 32, wc = (wave & 1) * 64;
  const int whalf = wave & 1;
  const int sr = lane >> 2;
  const int sc = ((lane & 3) ^ ((lane >> 3) & 3)) << 3;
  const u16* gA = X + (size_t)(row0 + wave * 16 + sr) * K + sc;
  const u16* gB0 = WT + (size_t)(wave * 16 + sr) * K + sc;
  const u16* gB1 = WT + (size_t)(64 + wave * 16 + sr) * K + sc;
  u16* lA0 = &lA[wave * 512];
  u16* lB0 = &lB[wave * 512];
  u16* lB1 = &lB[2048 + wave * 512];
  const int q = lane & 15;
  const int cg = lane >> 4;
  const int rdoff = ((cg ^ ((q >> 1) & 3)) << 3);
  f32x4 acc[2][4] = {};
  for (int k0 = 0; k0 < K; k0 += 32) {
    __syncthreads();
    GLOAD16(gA + k0, lA0);
    GLOAD16(gB0 + k0, lB0);
    GLOAD16(gB1 + k0, lB1);
    __syncthreads();
    bf16x8 af[2], bf[4];
    #pragma unroll
    for (int i = 0; i < 2; ++i)
      af[i] = *(const bf16x8*)&lA[(wr + i * 16 + q) * 32 + rdoff];
    #pragma unroll
    for (int j = 0; j < 4; ++j)
      bf[j] = *(const bf16x8*)&lB[(wc + j * 16 + q) * 32 + rdoff];
    #pragma unroll
    for (int i = 0; i < 2; ++i)
      #pragma unroll
      for (int j = 0; j < 4; ++j)
        acc[i][j] = __builtin_amdgcn_mfma_f32_16x16x32_bf16(af[i], bf[j], acc[i][j], 0, 0, 0);
  }
  const int rg4 = cg * 4;
  float ps[2][4], ps2[2][4];
  #pragma unroll
  for (int i = 0; i < 2; ++i)
    #pragma unroll
    for (int jj = 0; jj < 4; ++jj) { ps[i][jj] = 0.f; ps2[i][jj] = 0.f; }
  #pragma unroll
  for (int i = 0; i < 2; ++i) {
    #pragma unroll
    for (int j = 0; j < 4; ++j) {
      int col = wc + j * 16 + q;
      float bv = bias[col];
      #pragma unroll
      for (int jj = 0; jj < 4; ++jj) {
        int row = row0 + wr + i * 16 + rg4 + jj;
        float xv = bf2f(xio[(size_t)row * 128 + col]) + acc[i][j][jj] + bv;
        acc[i][j][jj] = xv;
        ps[i][jj] += xv;
        ps2[i][jj] += xv * xv;
      }
    }
  }
  #pragma unroll
  for (int o = 1; o < 16; o <<= 1) {
    #pragma unroll
    for (int i = 0; i < 2; ++i)
      #pragma unroll
      for (int jj = 0; jj < 4; ++jj) {
        ps[i][jj]  += __shfl_xor(ps[i][jj], o);
        ps2[i][jj] += __shfl_xor(ps2[i][jj], o);
      }
  }
  if (q == 0) {
    #pragma unroll
    for (int i = 0; i < 2; ++i)
      #pragma unroll
      for (int jj = 0; jj < 4; ++jj) {
        int rl = wr + i * 16 + rg4 + jj;
        part[rl][whalf][0] = ps[i][jj];
        part[rl][whalf][1] = ps2[i][jj];
      }
  }
  __syncthreads();
  #pragma unroll
  for (int i = 0; i < 2; ++i) {
    #pragma unroll
    for (int jj = 0; jj < 4; ++jj) {
      int rl = wr + i * 16 + rg4 + jj;
      float S  = part[rl][0][0] + part[rl][1][0];
      float S2 = part[rl][0][1] + part[rl][1][1];
      float mean = S * (1.f / 128.f);
      float rstd = rsqrtf(S2 * (1.f / 128.f) - mean * mean + 1e-5f);
      int row = row0 + rl;
      #pragma unroll
      for (int j = 0; j < 4; ++j) {
        int col = wc + j * 16 + q;
        float xv = acc[i][j][jj];
        xio[(size_t)row * 128 + col] = f2bf(xv);
        srcout[(size_t)row * 128 + col] = f2bf((xv - mean) * rstd * g[col] + be[col]);
      }
    }
  }
}

// ---------------------------------------------------------------- attention (32x32 MFMA flash)
// grid (BATCH, NHEAD): same-b blocks share an XCD L2. 576 threads = 9 waves,
// one q-tile per wave. Defer-max (THR=8, exp2 domain).
#define VSTR2 296
__global__ __launch_bounds__(576)
void k_attn(const u16* __restrict__ qkv, const int* __restrict__ mask,
            u16* __restrict__ out) {
  int b = blockIdx.x, h = blockIdx.y;
  __shared__ __align__(16) u16 Klin[9 * 512];
  __shared__ __align__(16) u16 Vt[16 * VSTR2];
  __shared__ int part[4];
  const int tid = threadIdx.x;
  if (tid < 256) {
    int mv = (mask[b * SEQL + tid] != 0) ? 1 : 0;
    #pragma unroll
    for (int o = 32; o; o >>= 1) mv += __shfl_xor(mv, o);
    if ((tid & 63) == 0) part[tid >> 6] = mv;
  }
  {
    int r = tid >> 1, h2 = tid & 1;
    uint4 val = make_uint4(0, 0, 0, 0);
    if (r < NPOS)
      val = *(const uint4*)&qkv[((size_t)(b * NPOS + r)) * 384 + h * 16 + 128 + h2 * 8];
    *(uint4*)&Klin[(r >> 5) * 512 + h2 * 256 + (r & 31) * 8] = val;
  }
  {
    // V staging spread across all 576 threads: 2 threads/row, 8 d each
    int r = tid >> 1, h2 = tid & 1;
    if (r < 288) {
      u16 tmp[8];
      if (r < NPOS) {
        *(uint4*)tmp = *(const uint4*)&qkv[((size_t)(b * NPOS + r)) * 384 + h * 16 + 256 + h2 * 8];
      } else {
        #pragma unroll
        for (int d = 0; d < 8; ++d) tmp[d] = 0;
      }
      #pragma unroll
      for (int d = 0; d < 8; ++d) Vt[(h2 * 8 + d) * VSTR2 + r] = tmp[d];
    }
  }
  __syncthreads();
  const int nvalid = part[0] + part[1] + part[2] + part[3] + 3;
  const int ktiles = (nvalid + 31) >> 5;
  const int wave = tid >> 6, lane = tid & 63;
  const int q5 = lane & 31, hi = lane >> 5;
  const f32x16 zf = {};
  const int qt = wave;
  int qrow = qt * 32 + q5;
  int qr = (qrow < NPOS) ? qrow : (NPOS - 1);
  bf16x8 qf = *(const bf16x8*)&qkv[((size_t)(b * NPOS + qr)) * 384 + h * 16 + hi * 8];
  float m = -1e30f, l = 0.f;
  f32x16 acc = {};
  for (int kt = 0; kt < ktiles; ++kt) {
    bf16x8 kf = *(const bf16x8*)&Klin[kt * 512 + lane * 8];
    __builtin_amdgcn_s_setprio(1);
    f32x16 s4 = __builtin_amdgcn_mfma_f32_32x32x16_bf16(kf, qf, zf, 0, 0, 0);
    __builtin_amdgcn_s_setprio(0);
    float p[16];
    float tmax = -1e30f;
    #pragma unroll
    for (int r = 0; r < 16; ++r) {
      int kr = kt * 32 + (r & 3) + 8 * (r >> 2) + 4 * hi;
      float v = (kr < nvalid) ? s4[r] : -1e30f;
      p[r] = v;
      tmax = fmaxf(tmax, v);
    }
    tmax = fmaxf(tmax, __shfl_xor(tmax, 32));
    bool defer = __all(tmax <= m + 8.f);
    float mnew = defer ? m : fmaxf(m, tmax);
    float fac = defer ? 1.f : exp2f(m - mnew);
    float tsum = 0.f;
    #pragma unroll
    for (int r = 0; r < 16; ++r) { p[r] = exp2f(p[r] - mnew); tsum += p[r]; }
    tsum += __shfl_xor(tsum, 32);
    l = l * fac + tsum;
    m = mnew;
    if (!defer) {
      #pragma unroll
      for (int r = 0; r < 8; ++r) acc[r] *= fac;
    }
    u32 w[8], xw[8];
    #pragma unroll
    for (int i = 0; i < 8; ++i)
      asm("v_cvt_pk_bf16_f32 %0, %1, %2" : "=v"(w[i]) : "v"(p[2 * i]), "v"(p[2 * i + 1]));
    #pragma unroll
    for (int i = 0; i < 8; ++i) xw[i] = (u32)__shfl_xor((int)w[i], 32);
    union { u32 u[4]; bf16x8 v; } f1, f2;
    if (hi) {
      f1.u[0] = xw[2]; f1.u[1] = xw[3]; f1.u[2] = w[2]; f1.u[3] = w[3];
      f2.u[0] = xw[6]; f2.u[1] = xw[7]; f2.u[2] = w[6]; f2.u[3] = w[7];
    } else {
      f1.u[0] = w[0]; f1.u[1] = w[1]; f1.u[2] = xw[0]; f1.u[3] = xw[1];
      f2.u[0] = w[4]; f2.u[1] = w[5]; f2.u[2] = xw[4]; f2.u[3] = xw[5];
    }
    bf16x8 vf0 = {}, vf1 = {};
    if (q5 < 16) {
      vf0 = *(const bf16x8*)&Vt[q5 * VSTR2 + kt * 32 + hi * 8];
      vf1 = *(const bf16x8*)&Vt[q5 * VSTR2 + kt * 32 + 16 + hi * 8];
    }
    __builtin_amdgcn_s_setprio(1);
    acc = __builtin_amdgcn_mfma_f32_32x32x16_bf16(vf0, f1.v, acc, 0, 0, 0);
    acc = __builtin_amdgcn_mfma_f32_32x32x16_bf16(vf1, f2.v, acc, 0, 0, 0);
    __builtin_amdgcn_s_setprio(0);
  }
  if (qrow < NPOS) {
    float linv = 1.f / l;
    u16* op = &out[((size_t)(b * NPOS + qrow)) * HD + h * 16];
    u32 w0 = (u32)f2bf(acc[0] * linv) | ((u32)f2bf(acc[1] * linv) << 16);
    u32 w1 = (u32)f2bf(acc[2] * linv) | ((u32)f2bf(acc[3] * linv) << 16);
    u32 w2 = (u32)f2bf(acc[4] * linv) | ((u32)f2bf(acc[5] * linv) << 16);
    u32 w3 = (u32)f2bf(acc[6] * linv) | ((u32)f2bf(acc[7] * linv) << 16);
    *(uint2*)&op[4 * hi] = make_uint2(w0, w1);
    *(uint2*)&op[8 + 4 * hi] = make_uint2(w2, w3);
  }
}

// ---------------------------------------------------------------- head (x bf16)
__global__ __launch_bounds__(128)
void k_head(const u16* __restrict__ x, const float* __restrict__ bw,
            const float* __restrict__ bb, const float* __restrict__ cw,
            const float* __restrict__ cb, float* __restrict__ dout) {
  int b = blockIdx.x, n = threadIdx.x;
  __shared__ float lat[HD];
  __shared__ float redp[2], redss[2];
  float lv = bf2f(x[((size_t)b * NPOS) * HD + n]);
  lat[n] = lv;
  __syncthreads();
  float t = 0.f;
  for (int k = 0; k < HD; ++k) t += lat[k] * bw[k * HD + n];
  t += bb[n];
  t = fmaxf(t, 0.f);
  float p = t * cw[n];
  float ss = lv * lv;
  #pragma unroll
  for (int o = 32; o; o >>= 1) { p += __shfl_xor(p, o); ss += __shfl_xor(ss, o); }
  if ((n & 63) == 0) { redp[n >> 6] = p; redss[n >> 6] = ss; }
  __syncthreads();
  float psum = redp[0] + redp[1];
  float ssum = redss[0] + redss[1];
  if (n == 0) dout[b] = psum + cb[0];
  float nrm = fmaxf(sqrtf(ssum), 1e-12f);
  dout[256 + (size_t)b * HD + n] = lv / nrm;
}

// ---------------------------------------------------------------- launch
extern "C" void kernel_launch(void* const* d_in, const int* in_sizes, int n_in,
                              void* d_out, int out_size, void* d_ws, size_t ws_size,
                              hipStream_t stream) {
  const int* item_seq = (const int*)d_in[0];
  const int* action_seq = (const int*)d_in[1];
  const int* time_diff = (const int*)d_in[2];
  const int* mask = (const int*)d_in[3];
  const int* u_cv = (const int*)d_in[4];
  const int* u_cl = (const int*)d_in[5];
  const float* u_num = (const float*)d_in[6];
  const int* i_cv = (const int*)d_in[7];
  const int* i_cl = (const int*)d_in[8];
  const float* i_num = (const float*)d_in[9];
  const float* item_t = (const float*)d_in[10];
  const float* act_t = (const float*)d_in[11];
  const float* time_t = (const float*)d_in[12];
  const float* cat_t = (const float*)d_in[13];
  const float* num_W = (const float*)d_in[14];
  const float* gtok = (const float*)d_in[15];
  const float* ln1_g = (const float*)d_in[16];
  const float* ln1_b = (const float*)d_in[17];
  const float* qkv_w = (const float*)d_in[18];
  const float* qkv_b = (const float*)d_in[19];
  const float* out_w = (const float*)d_in[20];
  const float* out_b = (const float*)d_in[21];
  const float* w1 = (const float*)d_in[22];
  const float* b1 = (const float*)d_in[23];
  const float* w2 = (const float*)d_in[24];
  const float* b2 = (const float*)d_in[25];
  const float* ln2_g = (const float*)d_in[26];
  const float* ln2_b = (const float*)d_in[27];
  const float* bott_w = (const float*)d_in[28];
  const float* bott_b = (const float*)d_in[29];
  const float* cls_w = (const float*)d_in[30];
  const float* cls_b = (const float*)d_in[31];

  // workspace layout (bytes)
  const size_t off_x   = 0;                    // TTOK*128 bf16 = 16,973,824 (residual, bf16)
  const size_t off_src = 16973824;             // TTOK*128 bf16 = 16,973,824
  const size_t off_big = 33947648;             // TTOK*512 bf16 = 67,895,296
  const size_t off_wT  = 101842944;            // 786,432 elems bf16 = 1,572,864
  const size_t need    = 103415808;
  if (ws_size < need) {
    fprintf(stderr, "kernel_launch: ws_size %zu < needed %zu\n", ws_size, need);
    return;
  }
  char* ws = (char*)d_ws;
  u16* x     = (u16*)(ws + off_x);
  u16* src   = (u16*)(ws + off_src);
  u16* big   = (u16*)(ws + off_big);
  u16* wT    = (u16*)(ws + off_wT);
  u16* qkvT  = wT;                 // [4][384][128]
  u16* outT  = wT + 196608;        // [4][128][128]
  u16* w1T   = wT + 262144;        // [4][512][128]
  u16* w2T   = wT + 524288;        // [4][128][512]

  k_transpose_all<<<3072, 256, 0, stream>>>(qkv_w, out_w, w1, w2, wT);

  k_build<<<dim3(NPOS, BATCH), 128, 0, stream>>>(
      item_seq, action_seq, time_diff, u_cv, u_cl, u_num, i_cv, i_cl, i_num,
      item_t, act_t, time_t, cat_t, num_W, gtok, ln1_g, ln1_b, x, src);

  const int rt = TTOK / 64;  // 1036
  for (int dd = 0; dd < DEPTH; ++dd) {
    // QKV (q cols pre-scaled by QSCALE): src -> big
    k_gemm_nres<3, 0, true><<<rt, 256, 0, stream>>>(
        src, qkvT + dd * 49152, qkv_b + dd * 384, big);
    // attention: big -> src
    k_attn<<<dim3(BATCH, NHEAD), 576, 0, stream>>>(big, mask, src);
    // proj + residual + fused LN2: src(attn) -> x, src(LN2 out)
    k_gemm_ln<<<rt, 256, 0, stream>>>(
        src, outT + dd * 16384, out_b + dd * HD, x,
        ln2_g + dd * HD, ln2_b + dd * HD, src, 128);
    // MLP1 (gelu): src -> big
    k_gemm_nres<4, 1, false><<<rt, 256, 0, stream>>>(
        src, w1T + dd * 65536, b1 + dd * FF, big);
    // MLP2 + residual + fused LN1 of next layer: big -> x, src
    const float* ng = (dd < 3) ? (ln1_g + (dd + 1) * HD) : (ln1_g + dd * HD);
    const float* nb = (dd < 3) ? (ln1_b + (dd + 1) * HD) : (ln1_b + dd * HD);
    k_gemm_ln<<<rt, 256, 0, stream>>>(
        big, w2T + dd * 65536, b2 + dd * HD, x, ng, nb, src, 512);
  }

  k_head<<<BATCH, 128, 0, stream>>>(x, bott_w, bott_b, cls_w, cls_b, (float*)d_out);
}

// Round 14
// 686.233 us; speedup vs baseline: 1.4830x; 1.0271x over previous
//
#include <hip/hip_runtime.h>
#include <cstdio>

// Problem constants
#define BATCH 256
#define SEQL 256
#define NPOS 259            // 3 + SEQL
#define TTOK (BATCH*NPOS)   // 66304 = 2072 * 32
#define HD 128
#define NHEAD 8
#define FF 512
#define DEPTH 4
#define CVOC 50001

typedef unsigned short u16;
typedef unsigned int u32;
typedef __bf16 bf16x8 __attribute__((ext_vector_type(8)));
typedef float f32x4 __attribute__((ext_vector_type(4)));
typedef float f32x16 __attribute__((ext_vector_type(16)));

typedef const __attribute__((address_space(1))) u32 gas_u32;
typedef __attribute__((address_space(3))) u32 las_u32;
#define GLOAD16(gptr, lptr) \
  __builtin_amdgcn_global_load_lds((gas_u32*)(gptr), (las_u32*)(lptr), 16, 0, 0)

// SCALE * log2(e): q pre-scaled so attention softmax can use native exp2
#define QSCALE 0.36067376022224085f

__device__ __forceinline__ u16 f2bf(float f) {
  u32 i = __float_as_uint(f);
  u32 r = (i + 0x7FFFu + ((i >> 16) & 1u)) >> 16;   // RNE
  return (u16)r;
}
__device__ __forceinline__ float bf2f(u16 u) {
  return __uint_as_float(((u32)u) << 16);
}

// ---------------------------------------------------------------- merged transpose + downcast
__global__ void k_transpose_all(const float* __restrict__ qkv_w, const float* __restrict__ out_w,
                                const float* __restrict__ w1, const float* __restrict__ w2,
                                u16* __restrict__ wT) {
  int idx = blockIdx.x * 256 + threadIdx.x;
  const float* in; int K, N, local;
  if (idx < 196608)      { in = qkv_w; K = 128; N = 384; local = idx; }
  else if (idx < 262144) { in = out_w; K = 128; N = 128; local = idx - 196608; }
  else if (idx < 524288) { in = w1;    K = 128; N = 512; local = idx - 262144; }
  else if (idx < 786432) { in = w2;    K = 512; N = 128; local = idx - 524288; }
  else return;
  int k = local % K; int rem = local / K; int n = rem % N; int d = rem / N;
  wT[idx] = f2bf(in[(d * K + k) * N + n]);
}

// ---------------------------------------------------------------- build x (+ fused layer-0 LN1)
__global__ __launch_bounds__(128)
void k_build(const int* __restrict__ item_seq, const int* __restrict__ act_seq,
             const int* __restrict__ tdiff,
             const int* __restrict__ ucv, const int* __restrict__ ucl, const float* __restrict__ unum,
             const int* __restrict__ icv, const int* __restrict__ icl, const float* __restrict__ inum,
             const float* __restrict__ item_t, const float* __restrict__ act_t,
             const float* __restrict__ time_t, const float* __restrict__ cat_t,
             const float* __restrict__ numW, const float* __restrict__ gtok,
             const float* __restrict__ g, const float* __restrict__ be,
             u16* __restrict__ x, u16* __restrict__ src) {
  int pos = blockIdx.x, b = blockIdx.y, h = threadIdx.x;
  float v;
  if (pos == 0) {
    v = gtok[h];
  } else if (pos <= 2) {
    const int* cv = (pos == 1) ? ucv : icv;
    const int* cl = (pos == 1) ? ucl : icl;
    const float* nm = (pos == 1) ? unum : inum;
    float acc = 0.f;
    for (int f = 0; f < 8; ++f) {
      float s = 0.f;
      for (int k = 0; k < 8; ++k) {
        int idx = cv[(b * 8 + f) * 8 + k];
        s += cat_t[((size_t)f * CVOC + idx) * HD + h];
      }
      acc += s / (float)cl[b * 8 + f];
    }
    for (int f = 0; f < 4; ++f)
      for (int d = 0; d < 32; ++d)
        acc += nm[(b * 4 + f) * 32 + d] * numW[(f * 32 + d) * HD + h];
    v = acc * (1.f / 12.f);
  } else {
    int l = pos - 3;
    v = item_t[(size_t)item_seq[b * SEQL + l] * HD + h]
      + act_t[(size_t)act_seq[b * SEQL + l] * HD + h]
      + time_t[(size_t)tdiff[b * SEQL + l] * HD + h];
  }
  size_t t = (size_t)b * NPOS + pos;
  x[t * HD + h] = f2bf(v);
  __shared__ float red[2][2];
  float s = v, s2 = v * v;
  #pragma unroll
  for (int o = 32; o; o >>= 1) { s += __shfl_xor(s, o); s2 += __shfl_xor(s2, o); }
  if ((h & 63) == 0) { red[h >> 6][0] = s; red[h >> 6][1] = s2; }
  __syncthreads();
  float S = red[0][0] + red[1][0], S2 = red[0][1] + red[1][1];
  float mean = S * (1.f / HD);
  float rstd = rsqrtf(S2 * (1.f / HD) - mean * mean + 1e-5f);
  src[t * HD + h] = f2bf((v - mean) * rstd * g[h] + be[h]);
}

// ---------------------------------------------------------------- GEMM, A-resident multi-N, 32-row tiles
// Y[32-row stripe x NCH*128] = act(X @ W + bias); WT[N][128] bf16, K=128.
// A (32x128) staged once (8KB); per n-chunk, B staged 8KB/k-step.
// Grid: TTOK/32 = 2072 blocks (~8/CU). Waves 2x2: 16 rows x 64 cols each.
template <int NCH, int ACT, bool QS>
__global__ __launch_bounds__(256)
void k_gemm_nres(const u16* __restrict__ X, const u16* __restrict__ WT,
                 const float* __restrict__ bias, u16* __restrict__ outp) {
  const int K = 128, N = NCH * 128;
  __shared__ __align__(16) u16 lA[4][32 * 32];   // [kt][row*32 + swz col]
  __shared__ __align__(16) u16 lB[128 * 32];
  const int tid = threadIdx.x;
  const int wave = tid >> 6, lane = tid & 63;
  const int row0 = blockIdx.x * 32;
  const int wr = (wave >> 1) * 16, wc = (wave & 1) * 64;
  const int sr = lane >> 2;
  const int sc = ((lane & 3) ^ ((lane >> 3) & 3)) << 3;
  const int q = lane & 15;
  const int cg = lane >> 4;
  const int rdoff = ((cg ^ ((q >> 1) & 3)) << 3);
  // stage full A: wave w stages k-subtile kt=w for both 16-row groups
  GLOAD16(X + (size_t)(row0 + sr) * K + wave * 32 + sc, &lA[wave][0]);
  GLOAD16(X + (size_t)(row0 + 16 + sr) * K + wave * 32 + sc, &lA[wave][512]);
  const u16* gB0 = WT + (size_t)(wave * 16 + sr) * K + sc;
  const u16* gB1 = WT + (size_t)(64 + wave * 16 + sr) * K + sc;
  u16* lB0 = &lB[wave * 512];
  u16* lB1 = &lB[2048 + wave * 512];
  for (int nc = 0; nc < NCH; ++nc) {
    const size_t nbase = (size_t)nc * 128 * K;
    f32x4 acc[4] = {};
    for (int k0 = 0; k0 < K; k0 += 32) {
      __syncthreads();
      GLOAD16(gB0 + nbase + k0, lB0);
      GLOAD16(gB1 + nbase + k0, lB1);
      __syncthreads();
      const int kt = k0 >> 5;
      bf16x8 af = *(const bf16x8*)&lA[kt][(wr + q) * 32 + rdoff];
      bf16x8 bf[4];
      #pragma unroll
      for (int j = 0; j < 4; ++j)
        bf[j] = *(const bf16x8*)&lB[(wc + j * 16 + q) * 32 + rdoff];
      #pragma unroll
      for (int j = 0; j < 4; ++j)
        acc[j] = __builtin_amdgcn_mfma_f32_16x16x32_bf16(af, bf[j], acc[j], 0, 0, 0);
    }
    const int rg4 = cg * 4;
    const float scl = (QS && nc == 0) ? QSCALE : 1.f;
    #pragma unroll
    for (int j = 0; j < 4; ++j) {
      int col = nc * 128 + wc + j * 16 + q;
      float bv = bias[col];
      #pragma unroll
      for (int jj = 0; jj < 4; ++jj) {
        int row = row0 + wr + rg4 + jj;
        float v = acc[j][jj] + bv;
        if (ACT == 1) v = 0.5f * v * (1.f + erff(v * 0.70710678118654752f));
        if (QS) v *= scl;
        outp[(size_t)row * N + col] = f2bf(v);
      }
    }
  }
}

// ---------------------------------------------------------------- residual GEMM + fused LN, 32-row tiles
// xnew = bf2f(xio) + X@WT + bias; xio (bf16) written back; srcout = LN(xnew) bf16.
__global__ __launch_bounds__(256)
void k_gemm_ln(const u16* __restrict__ X, const u16* __restrict__ WT,
               const float* __restrict__ bias, u16* __restrict__ xio,
               const float* __restrict__ g, const float* __restrict__ be,
               u16* __restrict__ srcout, int K) {
  __shared__ __align__(16) u16 lA[32 * 32];
  __shared__ __align__(16) u16 lB[128 * 32];
  __shared__ float part[32][2][2];
  const int tid = threadIdx.x;
  const int wave = tid >> 6, lane = tid & 63;
  const int row0 = blockIdx.x * 32;
  const int wr = (wave >> 1) * 16, wc = (wave & 1) * 64;
  const int whalf = wave & 1;
  const int sr = lane >> 2;
  const int sc = ((lane & 3) ^ ((lane >> 3) & 3)) << 3;
  const u16* gA = X + (size_t)(row0 + (wave & 1) * 16 + sr) * K + sc;  // waves 0,1 stage A rows 0-15,16-31
  const u16* gB0 = WT + (size_t)(wave * 16 + sr) * K + sc;
  const u16* gB1 = WT + (size_t)(64 + wave * 16 + sr) * K + sc;
  u16* lA0 = &lA[(wave & 1) * 512];
  u16* lB0 = &lB[wave * 512];
  u16* lB1 = &lB[2048 + wave * 512];
  const int q = lane & 15;
  const int cg = lane >> 4;
  const int rdoff = ((cg ^ ((q >> 1) & 3)) << 3);
  f32x4 acc[4] = {};
  for (int k0 = 0; k0 < K; k0 += 32) {
    __syncthreads();
    if (wave < 2) GLOAD16(gA + k0, lA0);
    GLOAD16(gB0 + k0, lB0);
    GLOAD16(gB1 + k0, lB1);
    __syncthreads();
    bf16x8 af = *(const bf16x8*)&lA[(wr + q) * 32 + rdoff];
    bf16x8 bf[4];
    #pragma unroll
    for (int j = 0; j < 4; ++j)
      bf[j] = *(const bf16x8*)&lB[(wc + j * 16 + q) * 32 + rdoff];
    #pragma unroll
    for (int j = 0; j < 4; ++j)
      acc[j] = __builtin_amdgcn_mfma_f32_16x16x32_bf16(af, bf[j], acc[j], 0, 0, 0);
  }
  const int rg4 = cg * 4;
  float ps[4], ps2[4];
  #pragma unroll
  for (int jj = 0; jj < 4; ++jj) { ps[jj] = 0.f; ps2[jj] = 0.f; }
  #pragma unroll
  for (int j = 0; j < 4; ++j) {
    int col = wc + j * 16 + q;
    float bv = bias[col];
    #pragma unroll
    for (int jj = 0; jj < 4; ++jj) {
      int row = row0 + wr + rg4 + jj;
      float xv = bf2f(xio[(size_t)row * 128 + col]) + acc[j][jj] + bv;
      acc[j][jj] = xv;
      ps[jj] += xv;
      ps2[jj] += xv * xv;
    }
  }
  #pragma unroll
  for (int o = 1; o < 16; o <<= 1) {
    #pragma unroll
    for (int jj = 0; jj < 4; ++jj) {
      ps[jj]  += __shfl_xor(ps[jj], o);
      ps2[jj] += __shfl_xor(ps2[jj], o);
    }
  }
  if (q == 0) {
    #pragma unroll
    for (int jj = 0; jj < 4; ++jj) {
      int rl = wr + rg4 + jj;
      part[rl][whalf][0] = ps[jj];
      part[rl][whalf][1] = ps2[jj];
    }
  }
  __syncthreads();
  #pragma unroll
  for (int jj = 0; jj < 4; ++jj) {
    int rl = wr + rg4 + jj;
    float S  = part[rl][0][0] + part[rl][1][0];
    float S2 = part[rl][0][1] + part[rl][1][1];
    float mean = S * (1.f / 128.f);
    float rstd = rsqrtf(S2 * (1.f / 128.f) - mean * mean + 1e-5f);
    int row = row0 + rl;
    #pragma unroll
    for (int j = 0; j < 4; ++j) {
      int col = wc + j * 16 + q;
      float xv = acc[j][jj];
      xio[(size_t)row * 128 + col] = f2bf(xv);
      srcout[(size_t)row * 128 + col] = f2bf((xv - mean) * rstd * g[col] + be[col]);
    }
  }
}

// ---------------------------------------------------------------- attention (32x32 MFMA flash)
// grid (BATCH, NHEAD); 576 threads = 9 waves, one q-tile per wave. Defer-max (THR=8).
// Full k-tiles take a no-mask fast path (block-uniform branch).
#define VSTR2 296
__global__ __launch_bounds__(576)
void k_attn(const u16* __restrict__ qkv, const int* __restrict__ mask,
            u16* __restrict__ out) {
  int b = blockIdx.x, h = blockIdx.y;
  __shared__ __align__(16) u16 Klin[9 * 512];
  __shared__ __align__(16) u16 Vt[16 * VSTR2];
  __shared__ int part[4];
  const int tid = threadIdx.x;
  if (tid < 256) {
    int mv = (mask[b * SEQL + tid] != 0) ? 1 : 0;
    #pragma unroll
    for (int o = 32; o; o >>= 1) mv += __shfl_xor(mv, o);
    if ((tid & 63) == 0) part[tid >> 6] = mv;
  }
  {
    int r = tid >> 1, h2 = tid & 1;
    uint4 val = make_uint4(0, 0, 0, 0);
    if (r < NPOS)
      val = *(const uint4*)&qkv[((size_t)(b * NPOS + r)) * 384 + h * 16 + 128 + h2 * 8];
    *(uint4*)&Klin[(r >> 5) * 512 + h2 * 256 + (r & 31) * 8] = val;
  }
  {
    int r = tid >> 1, h2 = tid & 1;
    if (r < 288) {
      u16 tmp[8];
      if (r < NPOS) {
        *(uint4*)tmp = *(const uint4*)&qkv[((size_t)(b * NPOS + r)) * 384 + h * 16 + 256 + h2 * 8];
      } else {
        #pragma unroll
        for (int d = 0; d < 8; ++d) tmp[d] = 0;
      }
      #pragma unroll
      for (int d = 0; d < 8; ++d) Vt[(h2 * 8 + d) * VSTR2 + r] = tmp[d];
    }
  }
  __syncthreads();
  const int nvalid = part[0] + part[1] + part[2] + part[3] + 3;
  const int ktiles = (nvalid + 31) >> 5;
  const int wave = tid >> 6, lane = tid & 63;
  const int q5 = lane & 31, hi = lane >> 5;
  const f32x16 zf = {};
  const int qt = wave;
  int qrow = qt * 32 + q5;
  int qr = (qrow < NPOS) ? qrow : (NPOS - 1);
  bf16x8 qf = *(const bf16x8*)&qkv[((size_t)(b * NPOS + qr)) * 384 + h * 16 + hi * 8];
  float m = -1e30f, l = 0.f;
  f32x16 acc = {};
  for (int kt = 0; kt < ktiles; ++kt) {
    bf16x8 kf = *(const bf16x8*)&Klin[kt * 512 + lane * 8];
    __builtin_amdgcn_s_setprio(1);
    f32x16 s4 = __builtin_amdgcn_mfma_f32_32x32x16_bf16(kf, qf, zf, 0, 0, 0);
    __builtin_amdgcn_s_setprio(0);
    float p[16];
    float tmax = -1e30f;
    if ((kt + 1) * 32 <= nvalid) {
      // full tile: no masking needed (block-uniform branch)
      #pragma unroll
      for (int r = 0; r < 16; ++r) { p[r] = s4[r]; tmax = fmaxf(tmax, s4[r]); }
    } else {
      #pragma unroll
      for (int r = 0; r < 16; ++r) {
        int kr = kt * 32 + (r & 3) + 8 * (r >> 2) + 4 * hi;
        float v = (kr < nvalid) ? s4[r] : -1e30f;
        p[r] = v;
        tmax = fmaxf(tmax, v);
      }
    }
    tmax = fmaxf(tmax, __shfl_xor(tmax, 32));
    bool defer = __all(tmax <= m + 8.f);
    float mnew = defer ? m : fmaxf(m, tmax);
    float fac = defer ? 1.f : exp2f(m - mnew);
    float tsum = 0.f;
    #pragma unroll
    for (int r = 0; r < 16; ++r) { p[r] = exp2f(p[r] - mnew); tsum += p[r]; }
    tsum += __shfl_xor(tsum, 32);
    l = l * fac + tsum;
    m = mnew;
    if (!defer) {
      #pragma unroll
      for (int r = 0; r < 8; ++r) acc[r] *= fac;
    }
    u32 w[8], xw[8];
    #pragma unroll
    for (int i = 0; i < 8; ++i)
      asm("v_cvt_pk_bf16_f32 %0, %1, %2" : "=v"(w[i]) : "v"(p[2 * i]), "v"(p[2 * i + 1]));
    #pragma unroll
    for (int i = 0; i < 8; ++i) xw[i] = (u32)__shfl_xor((int)w[i], 32);
    union { u32 u[4]; bf16x8 v; } f1, f2;
    if (hi) {
      f1.u[0] = xw[2]; f1.u[1] = xw[3]; f1.u[2] = w[2]; f1.u[3] = w[3];
      f2.u[0] = xw[6]; f2.u[1] = xw[7]; f2.u[2] = w[6]; f2.u[3] = w[7];
    } else {
      f1.u[0] = w[0]; f1.u[1] = w[1]; f1.u[2] = xw[0]; f1.u[3] = xw[1];
      f2.u[0] = w[4]; f2.u[1] = w[5]; f2.u[2] = xw[4]; f2.u[3] = xw[5];
    }
    bf16x8 vf0 = {}, vf1 = {};
    if (q5 < 16) {
      vf0 = *(const bf16x8*)&Vt[q5 * VSTR2 + kt * 32 + hi * 8];
      vf1 = *(const bf16x8*)&Vt[q5 * VSTR2 + kt * 32 + 16 + hi * 8];
    }
    __builtin_amdgcn_s_setprio(1);
    acc = __builtin_amdgcn_mfma_f32_32x32x16_bf16(vf0, f1.v, acc, 0, 0, 0);
    acc = __builtin_amdgcn_mfma_f32_32x32x16_bf16(vf1, f2.v, acc, 0, 0, 0);
    __builtin_amdgcn_s_setprio(0);
  }
  if (qrow < NPOS) {
    float linv = 1.f / l;
    u16* op = &out[((size_t)(b * NPOS + qrow)) * HD + h * 16];
    u32 w0 = (u32)f2bf(acc[0] * linv) | ((u32)f2bf(acc[1] * linv) << 16);
    u32 w1 = (u32)f2bf(acc[2] * linv) | ((u32)f2bf(acc[3] * linv) << 16);
    u32 w2 = (u32)f2bf(acc[4] * linv) | ((u32)f2bf(acc[5] * linv) << 16);
    u32 w3 = (u32)f2bf(acc[6] * linv) | ((u32)f2bf(acc[7] * linv) << 16);
    *(uint2*)&op[4 * hi] = make_uint2(w0, w1);
    *(uint2*)&op[8 + 4 * hi] = make_uint2(w2, w3);
  }
}

// ---------------------------------------------------------------- head (x bf16)
__global__ __launch_bounds__(128)
void k_head(const u16* __restrict__ x, const float* __restrict__ bw,
            const float* __restrict__ bb, const float* __restrict__ cw,
            const float* __restrict__ cb, float* __restrict__ dout) {
  int b = blockIdx.x, n = threadIdx.x;
  __shared__ float lat[HD];
  __shared__ float redp[2], redss[2];
  float lv = bf2f(x[((size_t)b * NPOS) * HD + n]);
  lat[n] = lv;
  __syncthreads();
  float t = 0.f;
  for (int k = 0; k < HD; ++k) t += lat[k] * bw[k * HD + n];
  t += bb[n];
  t = fmaxf(t, 0.f);
  float p = t * cw[n];
  float ss = lv * lv;
  #pragma unroll
  for (int o = 32; o; o >>= 1) { p += __shfl_xor(p, o); ss += __shfl_xor(ss, o); }
  if ((n & 63) == 0) { redp[n >> 6] = p; redss[n >> 6] = ss; }
  __syncthreads();
  float psum = redp[0] + redp[1];
  float ssum = redss[0] + redss[1];
  if (n == 0) dout[b] = psum + cb[0];
  float nrm = fmaxf(sqrtf(ssum), 1e-12f);
  dout[256 + (size_t)b * HD + n] = lv / nrm;
}

// ---------------------------------------------------------------- launch
extern "C" void kernel_launch(void* const* d_in, const int* in_sizes, int n_in,
                              void* d_out, int out_size, void* d_ws, size_t ws_size,
                              hipStream_t stream) {
  const int* item_seq = (const int*)d_in[0];
  const int* action_seq = (const int*)d_in[1];
  const int* time_diff = (const int*)d_in[2];
  const int* mask = (const int*)d_in[3];
  const int* u_cv = (const int*)d_in[4];
  const int* u_cl = (const int*)d_in[5];
  const float* u_num = (const float*)d_in[6];
  const int* i_cv = (const int*)d_in[7];
  const int* i_cl = (const int*)d_in[8];
  const float* i_num = (const float*)d_in[9];
  const float* item_t = (const float*)d_in[10];
  const float* act_t = (const float*)d_in[11];
  const float* time_t = (const float*)d_in[12];
  const float* cat_t = (const float*)d_in[13];
  const float* num_W = (const float*)d_in[14];
  const float* gtok = (const float*)d_in[15];
  const float* ln1_g = (const float*)d_in[16];
  const float* ln1_b = (const float*)d_in[17];
  const float* qkv_w = (const float*)d_in[18];
  const float* qkv_b = (const float*)d_in[19];
  const float* out_w = (const float*)d_in[20];
  const float* out_b = (const float*)d_in[21];
  const float* w1 = (const float*)d_in[22];
  const float* b1 = (const float*)d_in[23];
  const float* w2 = (const float*)d_in[24];
  const float* b2 = (const float*)d_in[25];
  const float* ln2_g = (const float*)d_in[26];
  const float* ln2_b = (const float*)d_in[27];
  const float* bott_w = (const float*)d_in[28];
  const float* bott_b = (const float*)d_in[29];
  const float* cls_w = (const float*)d_in[30];
  const float* cls_b = (const float*)d_in[31];

  // workspace layout (bytes)
  const size_t off_x   = 0;                    // TTOK*128 bf16 = 16,973,824 (residual)
  const size_t off_src = 16973824;             // TTOK*128 bf16 = 16,973,824
  const size_t off_big = 33947648;             // TTOK*512 bf16 = 67,895,296
  const size_t off_wT  = 101842944;            // 786,432 elems bf16 = 1,572,864
  const size_t need    = 103415808;
  if (ws_size < need) {
    fprintf(stderr, "kernel_launch: ws_size %zu < needed %zu\n", ws_size, need);
    return;
  }
  char* ws = (char*)d_ws;
  u16* x     = (u16*)(ws + off_x);
  u16* src   = (u16*)(ws + off_src);
  u16* big   = (u16*)(ws + off_big);
  u16* wT    = (u16*)(ws + off_wT);
  u16* qkvT  = wT;                 // [4][384][128]
  u16* outT  = wT + 196608;        // [4][128][128]
  u16* w1T   = wT + 262144;        // [4][512][128]
  u16* w2T   = wT + 524288;        // [4][128][512]

  k_transpose_all<<<3072, 256, 0, stream>>>(qkv_w, out_w, w1, w2, wT);

  k_build<<<dim3(NPOS, BATCH), 128, 0, stream>>>(
      item_seq, action_seq, time_diff, u_cv, u_cl, u_num, i_cv, i_cl, i_num,
      item_t, act_t, time_t, cat_t, num_W, gtok, ln1_g, ln1_b, x, src);

  const int rt = TTOK / 32;  // 2072
  for (int dd = 0; dd < DEPTH; ++dd) {
    // QKV (q cols pre-scaled by QSCALE): src -> big
    k_gemm_nres<3, 0, true><<<rt, 256, 0, stream>>>(
        src, qkvT + dd * 49152, qkv_b + dd * 384, big);
    // attention: big -> src
    k_attn<<<dim3(BATCH, NHEAD), 576, 0, stream>>>(big, mask, src);
    // proj + residual + fused LN2: src(attn) -> x, src(LN2 out)
    k_gemm_ln<<<rt, 256, 0, stream>>>(
        src, outT + dd * 16384, out_b + dd * HD, x,
        ln2_g + dd * HD, ln2_b + dd * HD, src, 128);
    // MLP1 (gelu): src -> big
    k_gemm_nres<4, 1, false><<<rt, 256, 0, stream>>>(
        src, w1T + dd * 65536, b1 + dd * FF, big);
    // MLP2 + residual + fused LN1 of next layer: big -> x, src
    const float* ng = (dd < 3) ? (ln1_g + (dd + 1) * HD) : (ln1_g + dd * HD);
    const float* nb = (dd < 3) ? (ln1_b + (dd + 1) * HD) : (ln1_b + dd * HD);
    k_gemm_ln<<<rt, 256, 0, stream>>>(
        big, w2T + dd * 65536, b2 + dd * HD, x, ng, nb, src, 512);
  }

  k_head<<<BATCH, 128, 0, stream>>>(x, bott_w, bott_b, cls_w, cls_b, (float*)d_out);
}

// Round 15
// 679.339 us; speedup vs baseline: 1.4981x; 1.0101x over previous
//
#include <hip/hip_runtime.h>
#include <cstdio>

// Problem constants
#define BATCH 256
#define SEQL 256
#define NPOS 259            // 3 + SEQL
#define TTOK (BATCH*NPOS)   // 66304 = 2072 * 32
#define HD 128
#define NHEAD 8
#define FF 512
#define DEPTH 4
#define CVOC 50001

typedef unsigned short u16;
typedef unsigned int u32;
typedef __bf16 bf16x8 __attribute__((ext_vector_type(8)));
typedef float f32x4 __attribute__((ext_vector_type(4)));
typedef float f32x16 __attribute__((ext_vector_type(16)));

typedef const __attribute__((address_space(1))) u32 gas_u32;
typedef __attribute__((address_space(3))) u32 las_u32;
#define GLOAD16(gptr, lptr) \
  __builtin_amdgcn_global_load_lds((gas_u32*)(gptr), (las_u32*)(lptr), 16, 0, 0)

// SCALE * log2(e): q pre-scaled so attention softmax can use native exp2
#define QSCALE 0.36067376022224085f

__device__ __forceinline__ u16 f2bf(float f) {
  u32 i = __float_as_uint(f);
  u32 r = (i + 0x7FFFu + ((i >> 16) & 1u)) >> 16;   // RNE
  return (u16)r;
}
__device__ __forceinline__ float bf2f(u16 u) {
  return __uint_as_float(((u32)u) << 16);
}

// ---------------------------------------------------------------- merged transpose + downcast
__global__ void k_transpose_all(const float* __restrict__ qkv_w, const float* __restrict__ out_w,
                                const float* __restrict__ w1, const float* __restrict__ w2,
                                u16* __restrict__ wT) {
  int idx = blockIdx.x * 256 + threadIdx.x;
  const float* in; int K, N, local;
  if (idx < 196608)      { in = qkv_w; K = 128; N = 384; local = idx; }
  else if (idx < 262144) { in = out_w; K = 128; N = 128; local = idx - 196608; }
  else if (idx < 524288) { in = w1;    K = 128; N = 512; local = idx - 262144; }
  else if (idx < 786432) { in = w2;    K = 512; N = 128; local = idx - 524288; }
  else return;
  int k = local % K; int rem = local / K; int n = rem % N; int d = rem / N;
  wT[idx] = f2bf(in[(d * K + k) * N + n]);
}

// ---------------------------------------------------------------- build x (+ fused layer-0 LN1)
__global__ __launch_bounds__(128)
void k_build(const int* __restrict__ item_seq, const int* __restrict__ act_seq,
             const int* __restrict__ tdiff,
             const int* __restrict__ ucv, const int* __restrict__ ucl, const float* __restrict__ unum,
             const int* __restrict__ icv, const int* __restrict__ icl, const float* __restrict__ inum,
             const float* __restrict__ item_t, const float* __restrict__ act_t,
             const float* __restrict__ time_t, const float* __restrict__ cat_t,
             const float* __restrict__ numW, const float* __restrict__ gtok,
             const float* __restrict__ g, const float* __restrict__ be,
             u16* __restrict__ x, u16* __restrict__ src) {
  int pos = blockIdx.x, b = blockIdx.y, h = threadIdx.x;
  float v;
  if (pos == 0) {
    v = gtok[h];
  } else if (pos <= 2) {
    const int* cv = (pos == 1) ? ucv : icv;
    const int* cl = (pos == 1) ? ucl : icl;
    const float* nm = (pos == 1) ? unum : inum;
    float acc = 0.f;
    for (int f = 0; f < 8; ++f) {
      float s = 0.f;
      for (int k = 0; k < 8; ++k) {
        int idx = cv[(b * 8 + f) * 8 + k];
        s += cat_t[((size_t)f * CVOC + idx) * HD + h];
      }
      acc += s / (float)cl[b * 8 + f];
    }
    for (int f = 0; f < 4; ++f)
      for (int d = 0; d < 32; ++d)
        acc += nm[(b * 4 + f) * 32 + d] * numW[(f * 32 + d) * HD + h];
    v = acc * (1.f / 12.f);
  } else {
    int l = pos - 3;
    v = item_t[(size_t)item_seq[b * SEQL + l] * HD + h]
      + act_t[(size_t)act_seq[b * SEQL + l] * HD + h]
      + time_t[(size_t)tdiff[b * SEQL + l] * HD + h];
  }
  size_t t = (size_t)b * NPOS + pos;
  x[t * HD + h] = f2bf(v);
  __shared__ float red[2][2];
  float s = v, s2 = v * v;
  #pragma unroll
  for (int o = 32; o; o >>= 1) { s += __shfl_xor(s, o); s2 += __shfl_xor(s2, o); }
  if ((h & 63) == 0) { red[h >> 6][0] = s; red[h >> 6][1] = s2; }
  __syncthreads();
  float S = red[0][0] + red[1][0], S2 = red[0][1] + red[1][1];
  float mean = S * (1.f / HD);
  float rstd = rsqrtf(S2 * (1.f / HD) - mean * mean + 1e-5f);
  src[t * HD + h] = f2bf((v - mean) * rstd * g[h] + be[h]);
}

// ---------------------------------------------------------------- GEMM, A-resident multi-N, 32-row tiles (layer-0 QKV)
template <int NCH, int ACT, bool QS>
__global__ __launch_bounds__(256)
void k_gemm_nres(const u16* __restrict__ X, const u16* __restrict__ WT,
                 const float* __restrict__ bias, u16* __restrict__ outp) {
  const int K = 128, N = NCH * 128;
  __shared__ __align__(16) u16 lA[4][32 * 32];
  __shared__ __align__(16) u16 lB[128 * 32];
  const int tid = threadIdx.x;
  const int wave = tid >> 6, lane = tid & 63;
  const int row0 = blockIdx.x * 32;
  const int wr = (wave >> 1) * 16, wc = (wave & 1) * 64;
  const int sr = lane >> 2;
  const int sc = ((lane & 3) ^ ((lane >> 3) & 3)) << 3;
  const int q = lane & 15;
  const int cg = lane >> 4;
  const int rdoff = ((cg ^ ((q >> 1) & 3)) << 3);
  GLOAD16(X + (size_t)(row0 + sr) * K + wave * 32 + sc, &lA[wave][0]);
  GLOAD16(X + (size_t)(row0 + 16 + sr) * K + wave * 32 + sc, &lA[wave][512]);
  const u16* gB0 = WT + (size_t)(wave * 16 + sr) * K + sc;
  const u16* gB1 = WT + (size_t)(64 + wave * 16 + sr) * K + sc;
  u16* lB0 = &lB[wave * 512];
  u16* lB1 = &lB[2048 + wave * 512];
  for (int nc = 0; nc < NCH; ++nc) {
    const size_t nbase = (size_t)nc * 128 * K;
    f32x4 acc[4] = {};
    for (int k0 = 0; k0 < K; k0 += 32) {
      __syncthreads();
      GLOAD16(gB0 + nbase + k0, lB0);
      GLOAD16(gB1 + nbase + k0, lB1);
      __syncthreads();
      const int kt = k0 >> 5;
      bf16x8 af = *(const bf16x8*)&lA[kt][(wr + q) * 32 + rdoff];
      bf16x8 bf[4];
      #pragma unroll
      for (int j = 0; j < 4; ++j)
        bf[j] = *(const bf16x8*)&lB[(wc + j * 16 + q) * 32 + rdoff];
      #pragma unroll
      for (int j = 0; j < 4; ++j)
        acc[j] = __builtin_amdgcn_mfma_f32_16x16x32_bf16(af, bf[j], acc[j], 0, 0, 0);
    }
    const int rg4 = cg * 4;
    const float scl = (QS && nc == 0) ? QSCALE : 1.f;
    #pragma unroll
    for (int j = 0; j < 4; ++j) {
      int col = nc * 128 + wc + j * 16 + q;
      float bv = bias[col];
      #pragma unroll
      for (int jj = 0; jj < 4; ++jj) {
        int row = row0 + wr + rg4 + jj;
        float v = acc[j][jj] + bv;
        if (ACT == 1) v = 0.5f * v * (1.f + erff(v * 0.70710678118654752f));
        if (QS) v *= scl;
        outp[(size_t)row * N + col] = f2bf(v);
      }
    }
  }
}

// ---------------------------------------------------------------- FUSED 32-row: residGEMM+LN -> LDS A -> multi-N GEMM
// Stage 1: xnew = bf2f(xio) + X@WT1 + bias1 (K1); xio bf16 written back; LN(g,be)
// scattered bf16 into swizzled lnA (never touches HBM).
// Stage 2: out2 = act2(LN @ WT2 + bias2), WT2 [NCH2*128][128]. Bit-identical to unfused pair.
// LDS 18.5KB -> 8 blocks/CU (full 32-wave occupancy).
template <int K1, int NCH2, int ACT2, bool QS2>
__global__ __launch_bounds__(256)
void k_fused(const u16* __restrict__ X, const u16* __restrict__ WT1,
             const float* __restrict__ bias1, u16* __restrict__ xio,
             const float* __restrict__ g, const float* __restrict__ be,
             const u16* __restrict__ WT2, const float* __restrict__ bias2,
             u16* __restrict__ out2) {
  __shared__ __align__(16) u16 lA[32 * 32];
  __shared__ __align__(16) u16 lB[128 * 32];
  __shared__ __align__(16) u16 lnA[4][32 * 32];
  __shared__ float part[32][2][2];
  const int tid = threadIdx.x;
  const int wave = tid >> 6, lane = tid & 63;
  const int row0 = blockIdx.x * 32;
  const int wr = (wave >> 1) * 16, wc = (wave & 1) * 64;
  const int whalf = wave & 1;
  const int sr = lane >> 2;
  const int sc = ((lane & 3) ^ ((lane >> 3) & 3)) << 3;
  const int q = lane & 15;
  const int cg = lane >> 4;
  const int rdoff = ((cg ^ ((q >> 1) & 3)) << 3);
  const int rg4 = cg * 4;
  // ---- stage 1: residual GEMM over K1
  {
    const u16* gA = X + (size_t)(row0 + (wave & 1) * 16 + sr) * K1 + sc;
    const u16* gB0 = WT1 + (size_t)(wave * 16 + sr) * K1 + sc;
    const u16* gB1 = WT1 + (size_t)(64 + wave * 16 + sr) * K1 + sc;
    u16* lA0 = &lA[(wave & 1) * 512];
    u16* lB0 = &lB[wave * 512];
    u16* lB1 = &lB[2048 + wave * 512];
    f32x4 acc[4] = {};
    for (int k0 = 0; k0 < K1; k0 += 32) {
      __syncthreads();
      if (wave < 2) GLOAD16(gA + k0, lA0);
      GLOAD16(gB0 + k0, lB0);
      GLOAD16(gB1 + k0, lB1);
      __syncthreads();
      bf16x8 af = *(const bf16x8*)&lA[(wr + q) * 32 + rdoff];
      bf16x8 bf[4];
      #pragma unroll
      for (int j = 0; j < 4; ++j)
        bf[j] = *(const bf16x8*)&lB[(wc + j * 16 + q) * 32 + rdoff];
      #pragma unroll
      for (int j = 0; j < 4; ++j)
        acc[j] = __builtin_amdgcn_mfma_f32_16x16x32_bf16(af, bf[j], acc[j], 0, 0, 0);
    }
    // residual add + LN stats
    float ps[4], ps2[4];
    #pragma unroll
    for (int jj = 0; jj < 4; ++jj) { ps[jj] = 0.f; ps2[jj] = 0.f; }
    #pragma unroll
    for (int j = 0; j < 4; ++j) {
      int col = wc + j * 16 + q;
      float bv = bias1[col];
      #pragma unroll
      for (int jj = 0; jj < 4; ++jj) {
        int row = row0 + wr + rg4 + jj;
        float xv = bf2f(xio[(size_t)row * 128 + col]) + acc[j][jj] + bv;
        acc[j][jj] = xv;
        ps[jj] += xv;
        ps2[jj] += xv * xv;
      }
    }
    #pragma unroll
    for (int o = 1; o < 16; o <<= 1) {
      #pragma unroll
      for (int jj = 0; jj < 4; ++jj) {
        ps[jj]  += __shfl_xor(ps[jj], o);
        ps2[jj] += __shfl_xor(ps2[jj], o);
      }
    }
    if (q == 0) {
      #pragma unroll
      for (int jj = 0; jj < 4; ++jj) {
        int rl = wr + rg4 + jj;
        part[rl][whalf][0] = ps[jj];
        part[rl][whalf][1] = ps2[jj];
      }
    }
    __syncthreads();
    #pragma unroll
    for (int jj = 0; jj < 4; ++jj) {
      int rl = wr + rg4 + jj;
      float S  = part[rl][0][0] + part[rl][1][0];
      float S2 = part[rl][0][1] + part[rl][1][1];
      float mean = S * (1.f / 128.f);
      float rstd = rsqrtf(S2 * (1.f / 128.f) - mean * mean + 1e-5f);
      int row = row0 + rl;
      const int rsel = ((rl >> 1) & 3) << 3;
      #pragma unroll
      for (int j = 0; j < 4; ++j) {
        int col = wc + j * 16 + q;
        float xv = acc[j][jj];
        xio[(size_t)row * 128 + col] = f2bf(xv);
        u16 lnv = f2bf((xv - mean) * rstd * g[col] + be[col]);
        // swizzled LDS scatter, bit-compatible with the stage-2 reader (R11-verified)
        lnA[col >> 5][rl * 32 + ((((col >> 3) & 3) << 3) ^ rsel) + (col & 7)] = lnv;
      }
    }
  }
  // ---- stage 2: lnA @ WT2, NCH2 chunks of 128 cols
  const u16* gB20 = WT2 + (size_t)(wave * 16 + sr) * 128 + sc;
  const u16* gB21 = WT2 + (size_t)(64 + wave * 16 + sr) * 128 + sc;
  u16* lB0 = &lB[wave * 512];
  u16* lB1 = &lB[2048 + wave * 512];
  for (int nc = 0; nc < NCH2; ++nc) {
    const size_t nbase = (size_t)nc * 128 * 128;
    f32x4 acc[4] = {};
    for (int k0 = 0; k0 < 128; k0 += 32) {
      __syncthreads();     // first iter: makes lnA writes visible; all: protects lB reuse
      GLOAD16(gB20 + nbase + k0, lB0);
      GLOAD16(gB21 + nbase + k0, lB1);
      __syncthreads();
      const int kt = k0 >> 5;
      bf16x8 af = *(const bf16x8*)&lnA[kt][(wr + q) * 32 + rdoff];
      bf16x8 bf[4];
      #pragma unroll
      for (int j = 0; j < 4; ++j)
        bf[j] = *(const bf16x8*)&lB[(wc + j * 16 + q) * 32 + rdoff];
      #pragma unroll
      for (int j = 0; j < 4; ++j)
        acc[j] = __builtin_amdgcn_mfma_f32_16x16x32_bf16(af, bf[j], acc[j], 0, 0, 0);
    }
    const float scl = (QS2 && nc == 0) ? QSCALE : 1.f;
    #pragma unroll
    for (int j = 0; j < 4; ++j) {
      int col = nc * 128 + wc + j * 16 + q;
      float bv = bias2[col];
      #pragma unroll
      for (int jj = 0; jj < 4; ++jj) {
        int row = row0 + wr + rg4 + jj;
        float v = acc[j][jj] + bv;
        if (ACT2 == 1) v = 0.5f * v * (1.f + erff(v * 0.70710678118654752f));
        if (QS2) v *= scl;
        out2[(size_t)row * (NCH2 * 128) + col] = f2bf(v);
      }
    }
  }
}

// ---------------------------------------------------------------- plain residual GEMM, 32-row (last MLP2)
__global__ __launch_bounds__(256)
void k_gemm_res(const u16* __restrict__ X, const u16* __restrict__ WT,
                const float* __restrict__ bias, u16* __restrict__ xio, int K) {
  __shared__ __align__(16) u16 lA[32 * 32];
  __shared__ __align__(16) u16 lB[128 * 32];
  const int tid = threadIdx.x;
  const int wave = tid >> 6, lane = tid & 63;
  const int row0 = blockIdx.x * 32;
  const int wr = (wave >> 1) * 16, wc = (wave & 1) * 64;
  const int sr = lane >> 2;
  const int sc = ((lane & 3) ^ ((lane >> 3) & 3)) << 3;
  const u16* gA = X + (size_t)(row0 + (wave & 1) * 16 + sr) * K + sc;
  const u16* gB0 = WT + (size_t)(wave * 16 + sr) * K + sc;
  const u16* gB1 = WT + (size_t)(64 + wave * 16 + sr) * K + sc;
  u16* lA0 = &lA[(wave & 1) * 512];
  u16* lB0 = &lB[wave * 512];
  u16* lB1 = &lB[2048 + wave * 512];
  const int q = lane & 15;
  const int cg = lane >> 4;
  const int rdoff = ((cg ^ ((q >> 1) & 3)) << 3);
  f32x4 acc[4] = {};
  for (int k0 = 0; k0 < K; k0 += 32) {
    __syncthreads();
    if (wave < 2) GLOAD16(gA + k0, lA0);
    GLOAD16(gB0 + k0, lB0);
    GLOAD16(gB1 + k0, lB1);
    __syncthreads();
    bf16x8 af = *(const bf16x8*)&lA[(wr + q) * 32 + rdoff];
    bf16x8 bf[4];
    #pragma unroll
    for (int j = 0; j < 4; ++j)
      bf[j] = *(const bf16x8*)&lB[(wc + j * 16 + q) * 32 + rdoff];
    #pragma unroll
    for (int j = 0; j < 4; ++j)
      acc[j] = __builtin_amdgcn_mfma_f32_16x16x32_bf16(af, bf[j], acc[j], 0, 0, 0);
  }
  const int rg4 = cg * 4;
  #pragma unroll
  for (int j = 0; j < 4; ++j) {
    int col = wc + j * 16 + q;
    float bv = bias[col];
    #pragma unroll
    for (int jj = 0; jj < 4; ++jj) {
      int row = row0 + wr + rg4 + jj;
      float xv = bf2f(xio[(size_t)row * 128 + col]) + acc[j][jj] + bv;
      xio[(size_t)row * 128 + col] = f2bf(xv);
    }
  }
}

// ---------------------------------------------------------------- attention (32x32 MFMA flash)
#define VSTR2 296
__global__ __launch_bounds__(576)
void k_attn(const u16* __restrict__ qkv, const int* __restrict__ mask,
            u16* __restrict__ out) {
  int b = blockIdx.x, h = blockIdx.y;
  __shared__ __align__(16) u16 Klin[9 * 512];
  __shared__ __align__(16) u16 Vt[16 * VSTR2];
  __shared__ int part[4];
  const int tid = threadIdx.x;
  if (tid < 256) {
    int mv = (mask[b * SEQL + tid] != 0) ? 1 : 0;
    #pragma unroll
    for (int o = 32; o; o >>= 1) mv += __shfl_xor(mv, o);
    if ((tid & 63) == 0) part[tid >> 6] = mv;
  }
  {
    int r = tid >> 1, h2 = tid & 1;
    uint4 val = make_uint4(0, 0, 0, 0);
    if (r < NPOS)
      val = *(const uint4*)&qkv[((size_t)(b * NPOS + r)) * 384 + h * 16 + 128 + h2 * 8];
    *(uint4*)&Klin[(r >> 5) * 512 + h2 * 256 + (r & 31) * 8] = val;
  }
  {
    int r = tid >> 1, h2 = tid & 1;
    if (r < 288) {
      u16 tmp[8];
      if (r < NPOS) {
        *(uint4*)tmp = *(const uint4*)&qkv[((size_t)(b * NPOS + r)) * 384 + h * 16 + 256 + h2 * 8];
      } else {
        #pragma unroll
        for (int d = 0; d < 8; ++d) tmp[d] = 0;
      }
      #pragma unroll
      for (int d = 0; d < 8; ++d) Vt[(h2 * 8 + d) * VSTR2 + r] = tmp[d];
    }
  }
  __syncthreads();
  const int nvalid = part[0] + part[1] + part[2] + part[3] + 3;
  const int ktiles = (nvalid + 31) >> 5;
  const int wave = tid >> 6, lane = tid & 63;
  const int q5 = lane & 31, hi = lane >> 5;
  const f32x16 zf = {};
  const int qt = wave;
  int qrow = qt * 32 + q5;
  int qr = (qrow < NPOS) ? qrow : (NPOS - 1);
  bf16x8 qf = *(const bf16x8*)&qkv[((size_t)(b * NPOS + qr)) * 384 + h * 16 + hi * 8];
  float m = -1e30f, l = 0.f;
  f32x16 acc = {};
  for (int kt = 0; kt < ktiles; ++kt) {
    bf16x8 kf = *(const bf16x8*)&Klin[kt * 512 + lane * 8];
    __builtin_amdgcn_s_setprio(1);
    f32x16 s4 = __builtin_amdgcn_mfma_f32_32x32x16_bf16(kf, qf, zf, 0, 0, 0);
    __builtin_amdgcn_s_setprio(0);
    float p[16];
    float tmax = -1e30f;
    if ((kt + 1) * 32 <= nvalid) {
      #pragma unroll
      for (int r = 0; r < 16; ++r) { p[r] = s4[r]; tmax = fmaxf(tmax, s4[r]); }
    } else {
      #pragma unroll
      for (int r = 0; r < 16; ++r) {
        int kr = kt * 32 + (r & 3) + 8 * (r >> 2) + 4 * hi;
        float v = (kr < nvalid) ? s4[r] : -1e30f;
        p[r] = v;
        tmax = fmaxf(tmax, v);
      }
    }
    tmax = fmaxf(tmax, __shfl_xor(tmax, 32));
    bool defer = __all(tmax <= m + 8.f);
    float mnew = defer ? m : fmaxf(m, tmax);
    float fac = defer ? 1.f : exp2f(m - mnew);
    float tsum = 0.f;
    #pragma unroll
    for (int r = 0; r < 16; ++r) { p[r] = exp2f(p[r] - mnew); tsum += p[r]; }
    tsum += __shfl_xor(tsum, 32);
    l = l * fac + tsum;
    m = mnew;
    if (!defer) {
      #pragma unroll
      for (int r = 0; r < 8; ++r) acc[r] *= fac;
    }
    u32 w[8], xw[8];
    #pragma unroll
    for (int i = 0; i < 8; ++i)
      asm("v_cvt_pk_bf16_f32 %0, %1, %2" : "=v"(w[i]) : "v"(p[2 * i]), "v"(p[2 * i + 1]));
    #pragma unroll
    for (int i = 0; i < 8; ++i) xw[i] = (u32)__shfl_xor((int)w[i], 32);
    union { u32 u[4]; bf16x8 v; } f1, f2;
    if (hi) {
      f1.u[0] = xw[2]; f1.u[1] = xw[3]; f1.u[2] = w[2]; f1.u[3] = w[3];
      f2.u[0] = xw[6]; f2.u[1] = xw[7]; f2.u[2] = w[6]; f2.u[3] = w[7];
    } else {
      f1.u[0] = w[0]; f1.u[1] = w[1]; f1.u[2] = xw[0]; f1.u[3] = xw[1];
      f2.u[0] = w[4]; f2.u[1] = w[5]; f2.u[2] = xw[4]; f2.u[3] = xw[5];
    }
    bf16x8 vf0 = {}, vf1 = {};
    if (q5 < 16) {
      vf0 = *(const bf16x8*)&Vt[q5 * VSTR2 + kt * 32 + hi * 8];
      vf1 = *(const bf16x8*)&Vt[q5 * VSTR2 + kt * 32 + 16 + hi * 8];
    }
    __builtin_amdgcn_s_setprio(1);
    acc = __builtin_amdgcn_mfma_f32_32x32x16_bf16(vf0, f1.v, acc, 0, 0, 0);
    acc = __builtin_amdgcn_mfma_f32_32x32x16_bf16(vf1, f2.v, acc, 0, 0, 0);
    __builtin_amdgcn_s_setprio(0);
  }
  if (qrow < NPOS) {
    float linv = 1.f / l;
    u16* op = &out[((size_t)(b * NPOS + qrow)) * HD + h * 16];
    u32 w0 = (u32)f2bf(acc[0] * linv) | ((u32)f2bf(acc[1] * linv) << 16);
    u32 w1 = (u32)f2bf(acc[2] * linv) | ((u32)f2bf(acc[3] * linv) << 16);
    u32 w2 = (u32)f2bf(acc[4] * linv) | ((u32)f2bf(acc[5] * linv) << 16);
    u32 w3 = (u32)f2bf(acc[6] * linv) | ((u32)f2bf(acc[7] * linv) << 16);
    *(uint2*)&op[4 * hi] = make_uint2(w0, w1);
    *(uint2*)&op[8 + 4 * hi] = make_uint2(w2, w3);
  }
}

// ---------------------------------------------------------------- head (x bf16)
__global__ __launch_bounds__(128)
void k_head(const u16* __restrict__ x, const float* __restrict__ bw,
            const float* __restrict__ bb, const float* __restrict__ cw,
            const float* __restrict__ cb, float* __restrict__ dout) {
  int b = blockIdx.x, n = threadIdx.x;
  __shared__ float lat[HD];
  __shared__ float redp[2], redss[2];
  float lv = bf2f(x[((size_t)b * NPOS) * HD + n]);
  lat[n] = lv;
  __syncthreads();
  float t = 0.f;
  for (int k = 0; k < HD; ++k) t += lat[k] * bw[k * HD + n];
  t += bb[n];
  t = fmaxf(t, 0.f);
  float p = t * cw[n];
  float ss = lv * lv;
  #pragma unroll
  for (int o = 32; o; o >>= 1) { p += __shfl_xor(p, o); ss += __shfl_xor(ss, o); }
  if ((n & 63) == 0) { redp[n >> 6] = p; redss[n >> 6] = ss; }
  __syncthreads();
  float psum = redp[0] + redp[1];
  float ssum = redss[0] + redss[1];
  if (n == 0) dout[b] = psum + cb[0];
  float nrm = fmaxf(sqrtf(ssum), 1e-12f);
  dout[256 + (size_t)b * HD + n] = lv / nrm;
}

// ---------------------------------------------------------------- launch
extern "C" void kernel_launch(void* const* d_in, const int* in_sizes, int n_in,
                              void* d_out, int out_size, void* d_ws, size_t ws_size,
                              hipStream_t stream) {
  const int* item_seq = (const int*)d_in[0];
  const int* action_seq = (const int*)d_in[1];
  const int* time_diff = (const int*)d_in[2];
  const int* mask = (const int*)d_in[3];
  const int* u_cv = (const int*)d_in[4];
  const int* u_cl = (const int*)d_in[5];
  const float* u_num = (const float*)d_in[6];
  const int* i_cv = (const int*)d_in[7];
  const int* i_cl = (const int*)d_in[8];
  const float* i_num = (const float*)d_in[9];
  const float* item_t = (const float*)d_in[10];
  const float* act_t = (const float*)d_in[11];
  const float* time_t = (const float*)d_in[12];
  const float* cat_t = (const float*)d_in[13];
  const float* num_W = (const float*)d_in[14];
  const float* gtok = (const float*)d_in[15];
  const float* ln1_g = (const float*)d_in[16];
  const float* ln1_b = (const float*)d_in[17];
  const float* qkv_w = (const float*)d_in[18];
  const float* qkv_b = (const float*)d_in[19];
  const float* out_w = (const float*)d_in[20];
  const float* out_b = (const float*)d_in[21];
  const float* w1 = (const float*)d_in[22];
  const float* b1 = (const float*)d_in[23];
  const float* w2 = (const float*)d_in[24];
  const float* b2 = (const float*)d_in[25];
  const float* ln2_g = (const float*)d_in[26];
  const float* ln2_b = (const float*)d_in[27];
  const float* bott_w = (const float*)d_in[28];
  const float* bott_b = (const float*)d_in[29];
  const float* cls_w = (const float*)d_in[30];
  const float* cls_b = (const float*)d_in[31];

  // workspace layout (bytes)
  const size_t off_x    = 0;                     // TTOK*128 bf16 = 16,973,824 (residual)
  const size_t off_src  = 16973824;              // TTOK*128 bf16 = 16,973,824 (LN1_0 out / attn out)
  const size_t off_h1   = 33947648;              // TTOK*512 bf16 = 67,895,296
  const size_t off_qkv  = 101842944;             // TTOK*384 bf16 = 50,921,472
  const size_t off_wT   = 152764416;             // 786,432 elems bf16 = 1,572,864
  const size_t need     = 154337280;
  if (ws_size < need) {
    fprintf(stderr, "kernel_launch: ws_size %zu < needed %zu\n", ws_size, need);
    return;
  }
  char* ws = (char*)d_ws;
  u16* x      = (u16*)(ws + off_x);
  u16* src    = (u16*)(ws + off_src);
  u16* h1buf  = (u16*)(ws + off_h1);
  u16* qkvbuf = (u16*)(ws + off_qkv);
  u16* wT     = (u16*)(ws + off_wT);
  u16* qkvT   = wT;                 // [4][384][128]
  u16* outT   = wT + 196608;        // [4][128][128]
  u16* w1T    = wT + 262144;        // [4][512][128]
  u16* w2T    = wT + 524288;        // [4][128][512]

  k_transpose_all<<<3072, 256, 0, stream>>>(qkv_w, out_w, w1, w2, wT);

  k_build<<<dim3(NPOS, BATCH), 128, 0, stream>>>(
      item_seq, action_seq, time_diff, u_cv, u_cl, u_num, i_cv, i_cl, i_num,
      item_t, act_t, time_t, cat_t, num_W, gtok, ln1_g, ln1_b, x, src);

  const int rt = TTOK / 32;  // 2072
  // layer-0 QKV (q cols pre-scaled): src -> qkvbuf
  k_gemm_nres<3, 0, true><<<rt, 256, 0, stream>>>(src, qkvT, qkv_b, qkvbuf);

  for (int dd = 0; dd < DEPTH; ++dd) {
    // attention: qkvbuf -> src
    k_attn<<<dim3(BATCH, NHEAD), 576, 0, stream>>>(qkvbuf, mask, src);
    // proj + residual + LN2 + MLP1(gelu): src -> x, h1buf
    k_fused<128, 4, 1, false><<<rt, 256, 0, stream>>>(
        src, outT + dd * 16384, out_b + dd * HD, x,
        ln2_g + dd * HD, ln2_b + dd * HD,
        w1T + dd * 65536, b1 + dd * FF, h1buf);
    if (dd < 3) {
      // MLP2 + residual + LN1(next) + QKV(next): h1buf -> x, qkvbuf
      k_fused<512, 3, 0, true><<<rt, 256, 0, stream>>>(
          h1buf, w2T + dd * 65536, b2 + dd * HD, x,
          ln1_g + (dd + 1) * HD, ln1_b + (dd + 1) * HD,
          qkvT + (dd + 1) * 49152, qkv_b + (dd + 1) * 384, qkvbuf);
    } else {
      // last MLP2: residual only
      k_gemm_res<<<rt, 256, 0, stream>>>(h1buf, w2T + dd * 65536, b2 + dd * HD, x, 512);
    }
  }

  k_head<<<BATCH, 128, 0, stream>>>(x, bott_w, bott_b, cls_w, cls_b, (float*)d_out);
}